// Round 2
// baseline (6076.267 us; speedup 1.0000x reference)
//
#include <hip/hip_runtime.h>

// ============================================================================
// Djpegnet round 1: fp32 full pipeline, workspace cut 503MB -> 124MB via
// batch chunking (suspected round-0 crash = d_ws overflow).
//  - dct_kernel: separable 8x8 block DCT.
//  - hist_kernel: gamma=1e6 sigmoid == step except within ~1e-4 of a bin edge
//    -> O(1) scatter per coeff into 16-way replicated LDS histogram.
//  - conv5_bn_relu<CI,CO,H,W,CK,WG_W,H_T>: direct 5x5 conv pad 2, fused
//    BN(eval)+ReLU, 4co x 16w register tile, LDS-staged weights+input.
//  - conv1 stage chunked x8 (16 imgs), conv2 x4 (32), conv3 x2 (64).
//  - fc1 split-K GEMM; fc1o/fc2o padded to stride 512 (float4 alignment).
// ============================================================================

// ---------------------------------------------------------------- DCT ------
__global__ __launch_bounds__(256) void dct_kernel(const float* __restrict__ x,
                                                  const float* __restrict__ basis,
                                                  float* __restrict__ dct) {
  __shared__ __align__(16) float Bm[64];  // Bm[u*8+xx] = a_u cos((2xx+1)u pi/16)
  int tid = threadIdx.x;
  if (tid < 64) {
    int u = tid >> 3, xx = tid & 7;
    // basis[(u*8+0)*64 + xx*8 + 0] = B[u,xx] * B[0,0], B[0,0]=sqrt(1/8)
    Bm[tid] = basis[(u * 8) * 64 + xx * 8] * 2.8284271247461903f;
  }
  __syncthreads();
  int gid = blockIdx.x * 256 + tid;     // 128 images * 1024 blocks
  int b = gid >> 10, blk = gid & 1023;
  int bi = blk >> 5, bj = blk & 31;
  const float* xp = x + (size_t)b * 65536 + (bi * 8) * 256 + bj * 8;
  float X[64];
#pragma unroll
  for (int r = 0; r < 8; ++r) {
    float4 p = *(const float4*)(xp + r * 256);
    float4 q = *(const float4*)(xp + r * 256 + 4);
    X[r * 8 + 0] = p.x; X[r * 8 + 1] = p.y; X[r * 8 + 2] = p.z; X[r * 8 + 3] = p.w;
    X[r * 8 + 4] = q.x; X[r * 8 + 5] = q.y; X[r * 8 + 6] = q.z; X[r * 8 + 7] = q.w;
  }
  float T[64];
#pragma unroll
  for (int u = 0; u < 8; ++u) {
    float t[8] = {0.f, 0.f, 0.f, 0.f, 0.f, 0.f, 0.f, 0.f};
#pragma unroll
    for (int xx = 0; xx < 8; ++xx) {
      float bm = Bm[u * 8 + xx];
#pragma unroll
      for (int y = 0; y < 8; ++y) t[y] += bm * X[xx * 8 + y];
    }
#pragma unroll
    for (int y = 0; y < 8; ++y) T[u * 8 + y] = t[y];
  }
  float* op = dct + (size_t)b * 65536 + bi * 32 + bj;
#pragma unroll
  for (int v = 0; v < 8; ++v) {
    float dc[8] = {0.f, 0.f, 0.f, 0.f, 0.f, 0.f, 0.f, 0.f};
#pragma unroll
    for (int y = 0; y < 8; ++y) {
      float bm = Bm[v * 8 + y];
#pragma unroll
      for (int u = 0; u < 8; ++u) dc[u] += bm * T[u * 8 + y];
    }
#pragma unroll
    for (int u = 0; u < 8; ++u) op[(u * 8 + v) * 1024] = dc[u];
  }
}

// ---------------------------------------------------- soft histogram -------
__global__ __launch_bounds__(256) void hist_kernel(const float* __restrict__ dct,
                                                   float* __restrict__ feat) {
  __shared__ __align__(16) float h[16 * 121];  // 16 replicas, stride 121
  int tid = threadIdx.x;
  for (int i = tid; i < 16 * 121; i += 256) h[i] = 0.f;
  __syncthreads();
  int b = blockIdx.x >> 6, c = blockIdx.x & 63;
  const float* dp = dct + (size_t)(b * 64 + c) * 1024;
  float* hc = h + (tid & 15) * 121;
  float4 v4 = ((const float4*)dp)[tid];
  float vals[4] = {v4.x, v4.y, v4.z, v4.w};
#pragma unroll
  for (int i = 0; i < 4; ++i) {
    float d = vals[i];
    float fl = floorf(d);
    float t0 = d - fl;        // exact (Sterbenz)
    int k = (int)fl + 60;     // feature bin of this coeff
    if (t0 >= 2e-5f && t0 <= 1.f - 1.2e-4f) {
      if (k >= 0 && k < 120) atomicAdd(hc + k, 1.0f);
    } else {
      float s0 = 1.f / (1.f + expf(-1e6f * t0));
      float s1 = 1.f / (1.f + expf(1e6f * (1.f - t0)));
      if (k >= 1 && k <= 120) atomicAdd(hc + k - 1, 1.f - s0);
      if (k >= 0 && k < 120)  atomicAdd(hc + k, s0 - s1);
      if (k >= -1 && k < 119) atomicAdd(hc + k + 1, s1);
    }
  }
  __syncthreads();
  for (int f = tid; f < 120; f += 256) {
    float s = 0.f;
#pragma unroll
    for (int l = 0; l < 16; ++l) s += h[l * 121 + f];
    feat[((size_t)b * 120 + f) * 64 + c] = s * (1.f / 1024.f);
  }
}

// ------------------------------------------- direct 5x5 conv + BN + ReLU ---
// Thread computes 4 co x 16 w for one h. 256 thr = 8 cogrp * WG_W * H_T.
// Batch count implicit from grid: grid = B * (CO/32) * ceil(H/H_T).
template <int CI, int CO, int H, int W, int CK, int WG_W, int H_T>
__global__ __launch_bounds__(256) void conv5_bn_relu(
    const float* __restrict__ in, const float* __restrict__ wts,
    const float* __restrict__ cb, const float* __restrict__ bns,
    const float* __restrict__ bnb, const float* __restrict__ bnm,
    const float* __restrict__ bnv, float* __restrict__ out) {
  constexpr int COT = 32, COG = 8;
  constexpr int WPAD = (W + 4 + 3) & ~3;
  constexpr int IROWS = H_T + 4;
  constexpr int NHT = (H + H_T - 1) / H_T;
  __shared__ __align__(16) float wlds[CK * 5 * COG * 20];  // [ci][kh][cog][co4*kw5]
  __shared__ __align__(16) float ilds[CK * IROWS * WPAD];
  int tid = threadIdx.x;
  int bid = blockIdx.x;
  constexpr int NCO = CO / COT;
  int b = bid / (NCO * NHT);
  int r = bid % (NCO * NHT);
  int cob = r / NHT;
  int h0 = (r % NHT) * H_T;
  int cog = tid & 7;
  int wg = (tid >> 3) % WG_W;
  int hh = tid / (8 * WG_W);
  float acc[4][16];
#pragma unroll
  for (int i = 0; i < 4; ++i)
#pragma unroll
    for (int j = 0; j < 16; ++j) acc[i][j] = 0.f;

#pragma unroll 1
  for (int ci0 = 0; ci0 < CI; ci0 += CK) {
    for (int idx = tid; idx < CK * COT * 25; idx += 256) {
      int rr = idx % 25;
      int t = idx / 25;
      int ci = t % CK;
      int co = t / CK;
      float v = wts[((size_t)(cob * COT + co) * CI + ci0 + ci) * 25 + rr];
      int kh = rr / 5, kw = rr % 5;
      wlds[((ci * 5 + kh) * COG + (co >> 2)) * 20 + (co & 3) * 5 + kw] = v;
    }
    for (int idx = tid; idx < CK * IROWS * WPAD; idx += 256) {
      int cc = idx % WPAD;
      int t = idx / WPAD;
      int rr2 = t % IROWS;
      int ci = t / IROWS;
      int hy = h0 + rr2 - 2;
      int wx = cc - 2;
      float v = 0.f;
      if (hy >= 0 && hy < H && wx >= 0 && wx < W)
        v = in[((size_t)(b * CI + ci0 + ci) * H + hy) * W + wx];
      ilds[idx] = v;
    }
    __syncthreads();
#pragma unroll 1
    for (int ci = 0; ci < CK; ++ci) {
#pragma unroll
      for (int kh = 0; kh < 5; ++kh) {
        const float* ir = &ilds[(ci * IROWS + hh + kh) * WPAD + wg * 16];
        float4 i0 = *(const float4*)ir;
        float4 i1 = *(const float4*)(ir + 4);
        float4 i2 = *(const float4*)(ir + 8);
        float4 i3 = *(const float4*)(ir + 12);
        float4 i4 = *(const float4*)(ir + 16);
        float iv[20] = {i0.x, i0.y, i0.z, i0.w, i1.x, i1.y, i1.z, i1.w,
                        i2.x, i2.y, i2.z, i2.w, i3.x, i3.y, i3.z, i3.w,
                        i4.x, i4.y, i4.z, i4.w};
        const float* wr = &wlds[((ci * 5 + kh) * COG + cog) * 20];
        float4 w0 = *(const float4*)wr;
        float4 w1 = *(const float4*)(wr + 4);
        float4 w2 = *(const float4*)(wr + 8);
        float4 w3 = *(const float4*)(wr + 12);
        float4 w4 = *(const float4*)(wr + 16);
        float wv[20] = {w0.x, w0.y, w0.z, w0.w, w1.x, w1.y, w1.z, w1.w,
                        w2.x, w2.y, w2.z, w2.w, w3.x, w3.y, w3.z, w3.w,
                        w4.x, w4.y, w4.z, w4.w};
#pragma unroll
        for (int co = 0; co < 4; ++co)
#pragma unroll
          for (int kw = 0; kw < 5; ++kw) {
            float wv1 = wv[co * 5 + kw];
#pragma unroll
            for (int w = 0; w < 16; ++w) acc[co][w] += wv1 * iv[w + kw];
          }
      }
    }
    __syncthreads();
  }
  int h = h0 + hh;
  if (h < H) {
#pragma unroll
    for (int co = 0; co < 4; ++co) {
      int gco = cob * COT + cog * 4 + co;
      float inv = bns[gco] * (1.f / sqrtf(bnv[gco] + 1e-5f));
      float bias = (cb[gco] - bnm[gco]) * inv + bnb[gco];
      float* op = out + ((size_t)(b * CO + gco) * H + h) * W + wg * 16;
#pragma unroll
      for (int w4 = 0; w4 < 4; ++w4) {
        float4 o;
        o.x = fmaxf(acc[co][w4 * 4 + 0] * inv + bias, 0.f);
        o.y = fmaxf(acc[co][w4 * 4 + 1] * inv + bias, 0.f);
        o.z = fmaxf(acc[co][w4 * 4 + 2] * inv + bias, 0.f);
        o.w = fmaxf(acc[co][w4 * 4 + 3] * inv + bias, 0.f);
        *(float4*)(op + w4 * 4) = o;
      }
    }
  }
}

// ------------------------------------------------------------- maxpool -----
template <int NBT, int C, int H, int W>
__global__ __launch_bounds__(256) void maxpool2(const float* __restrict__ in,
                                                float* __restrict__ out) {
  constexpr int OH = H / 2, OW = W / 2, OW4 = OW / 4;
  int idx = blockIdx.x * 256 + threadIdx.x;
  constexpr int TOTAL = NBT * C * OH * OW4;
  if (idx >= TOTAL) return;
  int w4 = idx % OW4;
  int t = idx / OW4;
  int h = t % OH; t /= OH;
  int c = t % C;
  int b = t / C;
  const float* p = in + ((size_t)(b * C + c) * H + 2 * h) * W + w4 * 8;
  float4 a0 = *(const float4*)p, a1 = *(const float4*)(p + 4);
  float4 b0 = *(const float4*)(p + W), b1 = *(const float4*)(p + W + 4);
  float4 o;
  o.x = fmaxf(fmaxf(a0.x, a0.y), fmaxf(b0.x, b0.y));
  o.y = fmaxf(fmaxf(a0.z, a0.w), fmaxf(b0.z, b0.w));
  o.z = fmaxf(fmaxf(a1.x, a1.y), fmaxf(b1.x, b1.y));
  o.w = fmaxf(fmaxf(a1.z, a1.w), fmaxf(b1.z, b1.w));
  *(float4*)(out + ((size_t)(b * C + c) * OH + h) * OW + w4 * 4) = o;
}

// --------------------------------------------------- fc1: split-K GEMM -----
__global__ __launch_bounds__(256) void fc1_partial(const float* __restrict__ qv,
                                                   const float* __restrict__ p3,
                                                   const float* __restrict__ w,
                                                   float* __restrict__ part) {
  __shared__ __align__(16) float As[128 * 36];
  __shared__ __align__(16) float Bs[128 * 36];
  int tid = threadIdx.x;
  int bid = blockIdx.x;
  int nt = bid & 3;
  int ks = bid >> 2;
  int n0 = nt * 128;
  int k0 = ks * 481, kend = k0 + 481;
  int tn = tid & 15, tm = tid >> 4;
  float acc[8][8];
#pragma unroll
  for (int i = 0; i < 8; ++i)
#pragma unroll
    for (int j = 0; j < 8; ++j) acc[i][j] = 0.f;
#pragma unroll 1
  for (int kc = k0; kc < kend; kc += 32) {
    for (int i = tid; i < 128 * 32; i += 256) {
      int kk = i & 31, mm = i >> 5;
      int k = kc + kk;
      float v = 0.f;
      if (k < kend) v = (k < 64) ? qv[mm * 64 + k] : p3[(size_t)mm * 30720 + (k - 64)];
      As[mm * 36 + kk] = v;
    }
    for (int i = tid; i < 128 * 32; i += 256) {
      int kk = i & 31, nn = i >> 5;
      int k = kc + kk, n = n0 + nn;
      float v = 0.f;
      if (k < kend && n < 500) v = w[(size_t)n * 30784 + k];
      Bs[nn * 36 + kk] = v;
    }
    __syncthreads();
#pragma unroll 2
    for (int kk = 0; kk < 32; kk += 4) {
      float4 av[8], bv[8];
#pragma unroll
      for (int i = 0; i < 8; ++i) av[i] = *(const float4*)&As[(tm + 16 * i) * 36 + kk];
#pragma unroll
      for (int j = 0; j < 8; ++j) bv[j] = *(const float4*)&Bs[(tn + 16 * j) * 36 + kk];
#pragma unroll
      for (int i = 0; i < 8; ++i)
#pragma unroll
        for (int j = 0; j < 8; ++j)
          acc[i][j] += av[i].x * bv[j].x + av[i].y * bv[j].y +
                       av[i].z * bv[j].z + av[i].w * bv[j].w;
    }
    __syncthreads();
  }
#pragma unroll
  for (int i = 0; i < 8; ++i)
#pragma unroll
    for (int j = 0; j < 8; ++j)
      part[((size_t)ks * 128 + tm + 16 * i) * 512 + n0 + tn + 16 * j] = acc[i][j];
}

__global__ __launch_bounds__(256) void fc1_reduce(const float* __restrict__ part,
                                                  const float* __restrict__ bias,
                                                  float* __restrict__ out) {
  int idx = blockIdx.x * 256 + threadIdx.x;
  if (idx >= 128 * 500) return;
  int m = idx / 500, n = idx % 500;
  float s = 0.f;
#pragma unroll 8
  for (int ks = 0; ks < 64; ++ks) s += part[((size_t)ks * 128 + m) * 512 + n];
  out[m * 512 + n] = fmaxf(s + bias[n], 0.f);   // stride 512 (alignment)
}

// -------------------------------------------------------- fc2 / fc3 --------
__global__ __launch_bounds__(256) void fc2_kernel(const float* __restrict__ qv,
                                                  const float* __restrict__ fc1o,
                                                  const float* __restrict__ w,
                                                  const float* __restrict__ bias,
                                                  float* __restrict__ out) {
  int idx = blockIdx.x * 256 + threadIdx.x;
  if (idx >= 128 * 500) return;
  int m = idx / 500, n = idx % 500;
  const float* wr = w + (size_t)n * 564;
  const float* aq = qv + m * 64;
  const float* ah = fc1o + (size_t)m * 512;     // stride 512
  float acc = 0.f;
#pragma unroll 4
  for (int k = 0; k < 64; k += 4) {
    float4 a = *(const float4*)(aq + k);
    float4 ww = *(const float4*)(wr + k);
    acc += a.x * ww.x + a.y * ww.y + a.z * ww.z + a.w * ww.w;
  }
#pragma unroll 4
  for (int k = 0; k < 500; k += 4) {
    float4 a = *(const float4*)(ah + k);
    float4 ww = *(const float4*)(wr + 64 + k);
    acc += a.x * ww.x + a.y * ww.y + a.z * ww.z + a.w * ww.w;
  }
  out[m * 512 + n] = fmaxf(acc + bias[n], 0.f); // stride 512
}

__global__ __launch_bounds__(256) void fc3_kernel(const float* __restrict__ qv,
                                                  const float* __restrict__ fc2o,
                                                  const float* __restrict__ w,
                                                  const float* __restrict__ bias,
                                                  float* __restrict__ out) {
  int tid = threadIdx.x;  // 256 = 128 m * 2 n
  int m = tid >> 1, n = tid & 1;
  const float* wr = w + (size_t)n * 564;
  const float* aq = qv + m * 64;
  const float* ah = fc2o + (size_t)m * 512;     // stride 512
  float acc = 0.f;
#pragma unroll 4
  for (int k = 0; k < 64; k += 4) {
    float4 a = *(const float4*)(aq + k);
    float4 ww = *(const float4*)(wr + k);
    acc += a.x * ww.x + a.y * ww.y + a.z * ww.z + a.w * ww.w;
  }
#pragma unroll 4
  for (int k = 0; k < 500; k += 4) {
    float4 a = *(const float4*)(ah + k);
    float4 ww = *(const float4*)(wr + 64 + k);
    acc += a.x * ww.x + a.y * ww.y + a.z * ww.z + a.w * ww.w;
  }
  out[m * 2 + n] = acc + bias[n];
}

// ----------------------------------------------------------- launcher ------
extern "C" void kernel_launch(void* const* d_in, const int* in_sizes, int n_in,
                              void* d_out, int out_size, void* d_ws, size_t ws_size,
                              hipStream_t stream) {
  (void)in_sizes; (void)n_in; (void)out_size; (void)ws_size;
  const float* x      = (const float*)d_in[0];
  const float* qv     = (const float*)d_in[1];
  const float* basis  = (const float*)d_in[2];
  const float* c1aw   = (const float*)d_in[3];
  const float* c1ab   = (const float*)d_in[4];
  const float* c1bw   = (const float*)d_in[5];
  const float* c1bb   = (const float*)d_in[6];
  const float* c2aw   = (const float*)d_in[7];
  const float* c2ab   = (const float*)d_in[8];
  const float* c3aw   = (const float*)d_in[9];
  const float* c3ab   = (const float*)d_in[10];
  const float* bn1a_s = (const float*)d_in[11];
  const float* bn1a_b = (const float*)d_in[12];
  const float* bn1a_m = (const float*)d_in[13];
  const float* bn1a_v = (const float*)d_in[14];
  const float* bn1b_s = (const float*)d_in[15];
  const float* bn1b_b = (const float*)d_in[16];
  const float* bn1b_m = (const float*)d_in[17];
  const float* bn1b_v = (const float*)d_in[18];
  const float* bn2a_s = (const float*)d_in[19];
  const float* bn2a_b = (const float*)d_in[20];
  const float* bn2a_m = (const float*)d_in[21];
  const float* bn2a_v = (const float*)d_in[22];
  const float* bn3a_s = (const float*)d_in[23];
  const float* bn3a_b = (const float*)d_in[24];
  const float* bn3a_m = (const float*)d_in[25];
  const float* bn3a_v = (const float*)d_in[26];
  const float* fc1w   = (const float*)d_in[27];
  const float* fc1b   = (const float*)d_in[28];
  const float* fc2w   = (const float*)d_in[29];
  const float* fc2b   = (const float*)d_in[30];
  const float* fc3w   = (const float*)d_in[31];
  const float* fc3b   = (const float*)d_in[32];

  // ---- workspace layout (floats), peak 32,440,320 fl = 124 MB ----
  float* ws = (float*)d_ws;
  float* p1   = ws;                  // 15,728,640   [conv1 out pooled, full B]
  float* feat = ws + 15728640;       //    983,040
  float* t1   = ws + 16711680;       //  7,864,320   [chunk scratch]
  float* t2   = ws + 24576000;       //  7,864,320
  float* dct  = ws + 16711680;       //  8,388,608   [aliases t1/t2, dead early]
  float* a3c  = ws + 16711680;       //  7,864,320   [phase C chunk]
  float* p2   = ws + 24576000;       //  7,864,320   [phase C -> D]
  float* a4c  = ws + 16711680;       //  7,864,320   [phase D chunk]
  float* p3   = ws;                  //  3,932,160   [phase D -> E, p1 dead]
  float* f1p  = ws + 3932160;        //  4,194,304
  float* f1o  = ws + 8388608;        //     65,536   (128 x 512 padded)
  float* f2o  = ws + 8454144;        //     65,536

  dct_kernel<<<512, 256, 0, stream>>>(x, basis, dct);
  hist_kernel<<<128 * 64, 256, 0, stream>>>(dct, feat);

  // ---- conv1a + conv1b + pool1, 8 chunks of 16 images ----
  for (int c = 0; c < 8; ++c) {
    const float* fin = feat + (size_t)c * 16 * 120 * 64;
    float* pout = p1 + (size_t)c * 16 * 64 * 60 * 32;
    conv5_bn_relu<1, 64, 120, 64, 1, 4, 8><<<16 * 2 * 15, 256, 0, stream>>>(
        fin, c1aw, c1ab, bn1a_s, bn1a_b, bn1a_m, bn1a_v, t1);
    conv5_bn_relu<64, 64, 120, 64, 8, 4, 8><<<16 * 2 * 15, 256, 0, stream>>>(
        t1, c1bw, c1bb, bn1b_s, bn1b_b, bn1b_m, bn1b_v, t2);
    maxpool2<16, 64, 120, 64><<<1920, 256, 0, stream>>>(t2, pout);
  }

  // ---- conv2a + pool2, 4 chunks of 32 images ----
  for (int c = 0; c < 4; ++c) {
    const float* pin = p1 + (size_t)c * 32 * 64 * 60 * 32;
    float* pout = p2 + (size_t)c * 32 * 128 * 30 * 16;
    conv5_bn_relu<64, 128, 60, 32, 8, 2, 16><<<32 * 4 * 4, 256, 0, stream>>>(
        pin, c2aw, c2ab, bn2a_s, bn2a_b, bn2a_m, bn2a_v, a3c);
    maxpool2<32, 128, 60, 32><<<1920, 256, 0, stream>>>(a3c, pout);
  }

  // ---- conv3a + pool3, 2 chunks of 64 images ----
  for (int c = 0; c < 2; ++c) {
    const float* pin = p2 + (size_t)c * 64 * 128 * 30 * 16;
    float* pout = p3 + (size_t)c * 64 * 256 * 15 * 8;
    conv5_bn_relu<128, 256, 30, 16, 8, 1, 32><<<64 * 8 * 1, 256, 0, stream>>>(
        pin, c3aw, c3ab, bn3a_s, bn3a_b, bn3a_m, bn3a_v, a4c);
    maxpool2<64, 256, 30, 16><<<1920, 256, 0, stream>>>(a4c, pout);
  }

  fc1_partial<<<4 * 64, 256, 0, stream>>>(qv, p3, fc1w, f1p);
  fc1_reduce<<<250, 256, 0, stream>>>(f1p, fc1b, f1o);
  fc2_kernel<<<250, 256, 0, stream>>>(qv, f1o, fc2w, fc2b, f2o);
  fc3_kernel<<<1, 256, 0, stream>>>(qv, f2o, fc3w, fc3b, (float*)d_out);
}

// Round 3
// 2386.871 us; speedup vs baseline: 2.5457x; 2.5457x over previous
//
#include <hip/hip_runtime.h>

// ============================================================================
// Djpegnet round 2: conv1b/2a/3a -> implicit-GEMM f16 MFMA (fp32 accumulate).
//  - GEMM roles: A = weights (M=co), B = activations (N=pixels) so C/D
//    (col=lane&31 = pixel) stores coalesced NCHW fp32.
//  - K-step 16 = (kw pair) x (8 ci). Weights pre-transposed to
//    [kh][kw6][co][ci] f16 with kw=5 slot zeroed; per ci-chunk(8) the whole
//    5x6 tap set for the block's co-range sits in LDS -> 2 barriers/chunk,
//    tap index folds into ds_read offset immediates (zero inner-loop VALU).
//  - Wave tile 64co x 128px = 8 acc tiles (32x32): 6x ds_read_b128 per
//    8 MFMA. All LDS reads 16B-stride -> bank-balanced.
//  - conv1a (CI=1) stays fp32 direct; dct/hist/pool/fc as round 1.
// Workspace peak ~135 MB (known-good ~130 MB in round 1).
// ============================================================================

typedef _Float16 half8 __attribute__((ext_vector_type(8)));
typedef float f32x16 __attribute__((ext_vector_type(16)));

// ---------------------------------------------------------------- DCT ------
__global__ __launch_bounds__(256) void dct_kernel(const float* __restrict__ x,
                                                  const float* __restrict__ basis,
                                                  float* __restrict__ dct) {
  __shared__ __align__(16) float Bm[64];
  int tid = threadIdx.x;
  if (tid < 64) {
    int u = tid >> 3, xx = tid & 7;
    Bm[tid] = basis[(u * 8) * 64 + xx * 8] * 2.8284271247461903f;
  }
  __syncthreads();
  int gid = blockIdx.x * 256 + tid;
  int b = gid >> 10, blk = gid & 1023;
  int bi = blk >> 5, bj = blk & 31;
  const float* xp = x + (size_t)b * 65536 + (bi * 8) * 256 + bj * 8;
  float X[64];
#pragma unroll
  for (int r = 0; r < 8; ++r) {
    float4 p = *(const float4*)(xp + r * 256);
    float4 q = *(const float4*)(xp + r * 256 + 4);
    X[r * 8 + 0] = p.x; X[r * 8 + 1] = p.y; X[r * 8 + 2] = p.z; X[r * 8 + 3] = p.w;
    X[r * 8 + 4] = q.x; X[r * 8 + 5] = q.y; X[r * 8 + 6] = q.z; X[r * 8 + 7] = q.w;
  }
  float T[64];
#pragma unroll
  for (int u = 0; u < 8; ++u) {
    float t[8] = {0.f, 0.f, 0.f, 0.f, 0.f, 0.f, 0.f, 0.f};
#pragma unroll
    for (int xx = 0; xx < 8; ++xx) {
      float bm = Bm[u * 8 + xx];
#pragma unroll
      for (int y = 0; y < 8; ++y) t[y] += bm * X[xx * 8 + y];
    }
#pragma unroll
    for (int y = 0; y < 8; ++y) T[u * 8 + y] = t[y];
  }
  float* op = dct + (size_t)b * 65536 + bi * 32 + bj;
#pragma unroll
  for (int v = 0; v < 8; ++v) {
    float dc[8] = {0.f, 0.f, 0.f, 0.f, 0.f, 0.f, 0.f, 0.f};
#pragma unroll
    for (int y = 0; y < 8; ++y) {
      float bm = Bm[v * 8 + y];
#pragma unroll
      for (int u = 0; u < 8; ++u) dc[u] += bm * T[u * 8 + y];
    }
#pragma unroll
    for (int u = 0; u < 8; ++u) op[(u * 8 + v) * 1024] = dc[u];
  }
}

// ---------------------------------------------------- soft histogram -------
__global__ __launch_bounds__(256) void hist_kernel(const float* __restrict__ dct,
                                                   float* __restrict__ feat) {
  __shared__ __align__(16) float h[16 * 121];
  int tid = threadIdx.x;
  for (int i = tid; i < 16 * 121; i += 256) h[i] = 0.f;
  __syncthreads();
  int b = blockIdx.x >> 6, c = blockIdx.x & 63;
  const float* dp = dct + (size_t)(b * 64 + c) * 1024;
  float* hc = h + (tid & 15) * 121;
  float4 v4 = ((const float4*)dp)[tid];
  float vals[4] = {v4.x, v4.y, v4.z, v4.w};
#pragma unroll
  for (int i = 0; i < 4; ++i) {
    float d = vals[i];
    float fl = floorf(d);
    float t0 = d - fl;
    int k = (int)fl + 60;
    if (t0 >= 2e-5f && t0 <= 1.f - 1.2e-4f) {
      if (k >= 0 && k < 120) atomicAdd(hc + k, 1.0f);
    } else {
      float s0 = 1.f / (1.f + expf(-1e6f * t0));
      float s1 = 1.f / (1.f + expf(1e6f * (1.f - t0)));
      if (k >= 1 && k <= 120) atomicAdd(hc + k - 1, 1.f - s0);
      if (k >= 0 && k < 120)  atomicAdd(hc + k, s0 - s1);
      if (k >= -1 && k < 119) atomicAdd(hc + k + 1, s1);
    }
  }
  __syncthreads();
  for (int f = tid; f < 120; f += 256) {
    float s = 0.f;
#pragma unroll
    for (int l = 0; l < 16; ++l) s += h[l * 121 + f];
    feat[((size_t)b * 120 + f) * 64 + c] = s * (1.f / 1024.f);
  }
}

// ---------------------------------------- weight transpose + BN folding ----
// wt[k30][co][ci] f16, k30 = kh*6 + kw (kw==5 slot zeroed).
template <int CI, int CO>
__global__ __launch_bounds__(256) void wtrans(const float* __restrict__ w,
                                              _Float16* __restrict__ wt) {
  int i = blockIdx.x * 256 + threadIdx.x;
  if (i >= 30 * CO * CI) return;
  int ci = i % CI;
  int t = i / CI;
  int co = t % CO;
  int k = t / CO;
  int kh = k / 6, kw = k % 6;
  float v = (kw < 5) ? w[((size_t)co * CI + ci) * 25 + kh * 5 + kw] : 0.f;
  wt[i] = (_Float16)v;
}

__global__ __launch_bounds__(256) void bnprep(const float* __restrict__ cb,
                                              const float* __restrict__ s,
                                              const float* __restrict__ b,
                                              const float* __restrict__ m,
                                              const float* __restrict__ v,
                                              float* __restrict__ scale,
                                              float* __restrict__ shift, int n) {
  int i = threadIdx.x;
  if (i < n) {
    float inv = s[i] * rsqrtf(v[i] + 1e-5f);
    scale[i] = inv;
    shift[i] = (cb[i] - m[i]) * inv + b[i];
  }
}

// -------------------------------- MFMA implicit-GEMM 5x5 conv + BN + ReLU --
// grid = nimg * TB * NCOB.  Block: 4 waves, wave = 64co x 128px.
template <int CI, int CO, int H, int W, int BLK_M>
__global__ __launch_bounds__(256, 2) void conv5_mfma(
    const float* __restrict__ in, const _Float16* __restrict__ wt,
    const float* __restrict__ scale, const float* __restrict__ shift,
    float* __restrict__ out) {
  constexpr int NW_M = BLK_M / 64;
  constexpr int NW_N = 4 / NW_M;
  constexpr int BLK_N = NW_N * 128;
  constexpr int ROWS = BLK_N / W;
  constexpr int TB = (H + ROWS - 1) / ROWS;
  constexpr int NCOB = CO / BLK_M;
  constexpr int HR = ROWS + 4;
  constexpr int HC = W + 4;
  __shared__ __align__(16) _Float16 Alds[HR * HC * 8 + 8];  // +8: kw=5 pad read slack
  __shared__ __align__(16) _Float16 Wlds[30 * BLK_M * 8];

  int tid = threadIdx.x;
  int bid = blockIdx.x;
  int img = bid / (TB * NCOB);
  int r = bid % (TB * NCOB);
  int tb = r / NCOB;
  int cob = r % NCOB;
  int h0 = tb * ROWS;

  int wid = tid >> 6, l = tid & 63, lo = l & 31, hi = l >> 5;
  int widM = wid / NW_N, widN = wid % NW_N;

  // per-lane LDS read bases (halves)
  int wbase[2];
#pragma unroll
  for (int mi = 0; mi < 2; ++mi)
    wbase[mi] = (hi * BLK_M + widM * 64 + mi * 32 + lo) * 8;
  int bbase[4], pr_[4], pc_[4];
#pragma unroll
  for (int j = 0; j < 4; ++j) {
    int pix = widN * 128 + j * 32 + lo;
    pr_[j] = pix / W;
    pc_[j] = pix % W;
    bbase[j] = (pr_[j] * HC + pc_[j] + hi) * 8;
  }

  f32x16 acc[2][4];
#pragma unroll
  for (int mi = 0; mi < 2; ++mi)
#pragma unroll
    for (int j = 0; j < 4; ++j) acc[mi][j] = (f32x16){};

#pragma unroll 1
  for (int ci0 = 0; ci0 < CI; ci0 += 8) {
    // ---- stage A tile: [r][c][ci8] f16 from NCHW fp32 (col-major loop for
    //      coalesced global reads) ----
    for (int i = tid; i < 8 * HR * HC; i += 256) {
      int ci = i / (HR * HC);
      int rc = i % (HR * HC);
      int rr = rc / HC, cc = rc % HC;
      int hy = h0 + rr - 2, wx = cc - 2;
      float v = 0.f;
      if (hy >= 0 && hy < H && wx >= 0 && wx < W)
        v = in[((size_t)(img * CI + ci0 + ci) * H + hy) * W + wx];
      Alds[rc * 8 + ci] = (_Float16)v;
    }
    // ---- stage W: all 30 taps for this co-range, ci0..ci0+7 ----
    for (int i = tid; i < 30 * BLK_M; i += 256) {
      int k = i / BLK_M, co = i % BLK_M;
      *(half8*)&Wlds[i * 8] =
          *(const half8*)&wt[((size_t)k * CO + cob * BLK_M + co) * CI + ci0];
    }
    __syncthreads();
#pragma unroll
    for (int kh = 0; kh < 5; ++kh) {
#pragma unroll
      for (int kwb = 0; kwb < 3; ++kwb) {
        half8 af[2], bf[4];
#pragma unroll
        for (int mi = 0; mi < 2; ++mi)
          af[mi] = *(const half8*)&Wlds[wbase[mi] + (kh * 6 + 2 * kwb) * BLK_M * 8];
#pragma unroll
        for (int j = 0; j < 4; ++j)
          bf[j] = *(const half8*)&Alds[bbase[j] + (kh * HC + 2 * kwb) * 8];
#pragma unroll
        for (int mi = 0; mi < 2; ++mi)
#pragma unroll
          for (int j = 0; j < 4; ++j)
            acc[mi][j] = __builtin_amdgcn_mfma_f32_32x32x16_f16(
                af[mi], bf[j], acc[mi][j], 0, 0, 0);
      }
    }
    __syncthreads();
  }

  // ---- epilogue: BN + ReLU, coalesced NCHW fp32 stores ----
#pragma unroll
  for (int mi = 0; mi < 2; ++mi) {
#pragma unroll
    for (int reg = 0; reg < 16; ++reg) {
      int co = cob * BLK_M + widM * 64 + mi * 32 + (reg & 3) + 8 * (reg >> 2) + 4 * hi;
      float s = scale[co], t = shift[co];
#pragma unroll
      for (int j = 0; j < 4; ++j) {
        int hy = h0 + pr_[j];
        if (hy < H)
          out[((size_t)(img * CO + co) * H + hy) * W + pc_[j]] =
              fmaxf(acc[mi][j][reg] * s + t, 0.f);
      }
    }
  }
}

// ------------------------------------------- direct 5x5 conv (conv1a) ------
template <int CI, int CO, int H, int W, int CK, int WG_W, int H_T>
__global__ __launch_bounds__(256) void conv5_bn_relu(
    const float* __restrict__ in, const float* __restrict__ wts,
    const float* __restrict__ cb, const float* __restrict__ bns,
    const float* __restrict__ bnb, const float* __restrict__ bnm,
    const float* __restrict__ bnv, float* __restrict__ out) {
  constexpr int COT = 32, COG = 8;
  constexpr int WPAD = (W + 4 + 3) & ~3;
  constexpr int IROWS = H_T + 4;
  constexpr int NHT = (H + H_T - 1) / H_T;
  __shared__ __align__(16) float wlds[CK * 5 * COG * 20];
  __shared__ __align__(16) float ilds[CK * IROWS * WPAD];
  int tid = threadIdx.x;
  int bid = blockIdx.x;
  constexpr int NCO = CO / COT;
  int b = bid / (NCO * NHT);
  int r = bid % (NCO * NHT);
  int cob = r / NHT;
  int h0 = (r % NHT) * H_T;
  int cog = tid & 7;
  int wg = (tid >> 3) % WG_W;
  int hh = tid / (8 * WG_W);
  float acc[4][16];
#pragma unroll
  for (int i = 0; i < 4; ++i)
#pragma unroll
    for (int j = 0; j < 16; ++j) acc[i][j] = 0.f;

#pragma unroll 1
  for (int ci0 = 0; ci0 < CI; ci0 += CK) {
    for (int idx = tid; idx < CK * COT * 25; idx += 256) {
      int rr = idx % 25;
      int t = idx / 25;
      int ci = t % CK;
      int co = t / CK;
      float v = wts[((size_t)(cob * COT + co) * CI + ci0 + ci) * 25 + rr];
      int kh = rr / 5, kw = rr % 5;
      wlds[((ci * 5 + kh) * COG + (co >> 2)) * 20 + (co & 3) * 5 + kw] = v;
    }
    for (int idx = tid; idx < CK * IROWS * WPAD; idx += 256) {
      int cc = idx % WPAD;
      int t = idx / WPAD;
      int rr2 = t % IROWS;
      int ci = t / IROWS;
      int hy = h0 + rr2 - 2;
      int wx = cc - 2;
      float v = 0.f;
      if (hy >= 0 && hy < H && wx >= 0 && wx < W)
        v = in[((size_t)(b * CI + ci0 + ci) * H + hy) * W + wx];
      ilds[idx] = v;
    }
    __syncthreads();
#pragma unroll 1
    for (int ci = 0; ci < CK; ++ci) {
#pragma unroll
      for (int kh = 0; kh < 5; ++kh) {
        const float* ir = &ilds[(ci * IROWS + hh + kh) * WPAD + wg * 16];
        float4 i0 = *(const float4*)ir;
        float4 i1 = *(const float4*)(ir + 4);
        float4 i2 = *(const float4*)(ir + 8);
        float4 i3 = *(const float4*)(ir + 12);
        float4 i4 = *(const float4*)(ir + 16);
        float iv[20] = {i0.x, i0.y, i0.z, i0.w, i1.x, i1.y, i1.z, i1.w,
                        i2.x, i2.y, i2.z, i2.w, i3.x, i3.y, i3.z, i3.w,
                        i4.x, i4.y, i4.z, i4.w};
        const float* wr = &wlds[((ci * 5 + kh) * COG + cog) * 20];
        float4 w0 = *(const float4*)wr;
        float4 w1 = *(const float4*)(wr + 4);
        float4 w2 = *(const float4*)(wr + 8);
        float4 w3 = *(const float4*)(wr + 12);
        float4 w4 = *(const float4*)(wr + 16);
        float wv[20] = {w0.x, w0.y, w0.z, w0.w, w1.x, w1.y, w1.z, w1.w,
                        w2.x, w2.y, w2.z, w2.w, w3.x, w3.y, w3.z, w3.w,
                        w4.x, w4.y, w4.z, w4.w};
#pragma unroll
        for (int co = 0; co < 4; ++co)
#pragma unroll
          for (int kw = 0; kw < 5; ++kw) {
            float wv1 = wv[co * 5 + kw];
#pragma unroll
            for (int w = 0; w < 16; ++w) acc[co][w] += wv1 * iv[w + kw];
          }
      }
    }
    __syncthreads();
  }
  int h = h0 + hh;
  if (h < H) {
#pragma unroll
    for (int co = 0; co < 4; ++co) {
      int gco = cob * COT + cog * 4 + co;
      float inv = bns[gco] * (1.f / sqrtf(bnv[gco] + 1e-5f));
      float bias = (cb[gco] - bnm[gco]) * inv + bnb[gco];
      float* op = out + ((size_t)(b * CO + gco) * H + h) * W + wg * 16;
#pragma unroll
      for (int w4 = 0; w4 < 4; ++w4) {
        float4 o;
        o.x = fmaxf(acc[co][w4 * 4 + 0] * inv + bias, 0.f);
        o.y = fmaxf(acc[co][w4 * 4 + 1] * inv + bias, 0.f);
        o.z = fmaxf(acc[co][w4 * 4 + 2] * inv + bias, 0.f);
        o.w = fmaxf(acc[co][w4 * 4 + 3] * inv + bias, 0.f);
        *(float4*)(op + w4 * 4) = o;
      }
    }
  }
}

// ------------------------------------------------------------- maxpool -----
template <int NBT, int C, int H, int W>
__global__ __launch_bounds__(256) void maxpool2(const float* __restrict__ in,
                                                float* __restrict__ out) {
  constexpr int OH = H / 2, OW = W / 2, OW4 = OW / 4;
  int idx = blockIdx.x * 256 + threadIdx.x;
  constexpr int TOTAL = NBT * C * OH * OW4;
  if (idx >= TOTAL) return;
  int w4 = idx % OW4;
  int t = idx / OW4;
  int h = t % OH; t /= OH;
  int c = t % C;
  int b = t / C;
  const float* p = in + ((size_t)(b * C + c) * H + 2 * h) * W + w4 * 8;
  float4 a0 = *(const float4*)p, a1 = *(const float4*)(p + 4);
  float4 b0 = *(const float4*)(p + W), b1 = *(const float4*)(p + W + 4);
  float4 o;
  o.x = fmaxf(fmaxf(a0.x, a0.y), fmaxf(b0.x, b0.y));
  o.y = fmaxf(fmaxf(a0.z, a0.w), fmaxf(b0.z, b0.w));
  o.z = fmaxf(fmaxf(a1.x, a1.y), fmaxf(b1.x, b1.y));
  o.w = fmaxf(fmaxf(a1.z, a1.w), fmaxf(b1.z, b1.w));
  *(float4*)(out + ((size_t)(b * C + c) * OH + h) * OW + w4 * 4) = o;
}

// --------------------------------------------------- fc1: split-K GEMM -----
__global__ __launch_bounds__(256) void fc1_partial(const float* __restrict__ qv,
                                                   const float* __restrict__ p3,
                                                   const float* __restrict__ w,
                                                   float* __restrict__ part) {
  __shared__ __align__(16) float As[128 * 36];
  __shared__ __align__(16) float Bs[128 * 36];
  int tid = threadIdx.x;
  int bid = blockIdx.x;
  int nt = bid & 3;
  int ks = bid >> 2;
  int n0 = nt * 128;
  int k0 = ks * 481, kend = k0 + 481;
  int tn = tid & 15, tm = tid >> 4;
  float acc[8][8];
#pragma unroll
  for (int i = 0; i < 8; ++i)
#pragma unroll
    for (int j = 0; j < 8; ++j) acc[i][j] = 0.f;
#pragma unroll 1
  for (int kc = k0; kc < kend; kc += 32) {
    for (int i = tid; i < 128 * 32; i += 256) {
      int kk = i & 31, mm = i >> 5;
      int k = kc + kk;
      float v = 0.f;
      if (k < kend) v = (k < 64) ? qv[mm * 64 + k] : p3[(size_t)mm * 30720 + (k - 64)];
      As[mm * 36 + kk] = v;
    }
    for (int i = tid; i < 128 * 32; i += 256) {
      int kk = i & 31, nn = i >> 5;
      int k = kc + kk, n = n0 + nn;
      float v = 0.f;
      if (k < kend && n < 500) v = w[(size_t)n * 30784 + k];
      Bs[nn * 36 + kk] = v;
    }
    __syncthreads();
#pragma unroll 2
    for (int kk = 0; kk < 32; kk += 4) {
      float4 av[8], bv[8];
#pragma unroll
      for (int i = 0; i < 8; ++i) av[i] = *(const float4*)&As[(tm + 16 * i) * 36 + kk];
#pragma unroll
      for (int j = 0; j < 8; ++j) bv[j] = *(const float4*)&Bs[(tn + 16 * j) * 36 + kk];
#pragma unroll
      for (int i = 0; i < 8; ++i)
#pragma unroll
        for (int j = 0; j < 8; ++j)
          acc[i][j] += av[i].x * bv[j].x + av[i].y * bv[j].y +
                       av[i].z * bv[j].z + av[i].w * bv[j].w;
    }
    __syncthreads();
  }
#pragma unroll
  for (int i = 0; i < 8; ++i)
#pragma unroll
    for (int j = 0; j < 8; ++j)
      part[((size_t)ks * 128 + tm + 16 * i) * 512 + n0 + tn + 16 * j] = acc[i][j];
}

__global__ __launch_bounds__(256) void fc1_reduce(const float* __restrict__ part,
                                                  const float* __restrict__ bias,
                                                  float* __restrict__ out) {
  int idx = blockIdx.x * 256 + threadIdx.x;
  if (idx >= 128 * 500) return;
  int m = idx / 500, n = idx % 500;
  float s = 0.f;
#pragma unroll 8
  for (int ks = 0; ks < 64; ++ks) s += part[((size_t)ks * 128 + m) * 512 + n];
  out[m * 512 + n] = fmaxf(s + bias[n], 0.f);
}

// -------------------------------------------------------- fc2 / fc3 --------
__global__ __launch_bounds__(256) void fc2_kernel(const float* __restrict__ qv,
                                                  const float* __restrict__ fc1o,
                                                  const float* __restrict__ w,
                                                  const float* __restrict__ bias,
                                                  float* __restrict__ out) {
  int idx = blockIdx.x * 256 + threadIdx.x;
  if (idx >= 128 * 500) return;
  int m = idx / 500, n = idx % 500;
  const float* wr = w + (size_t)n * 564;
  const float* aq = qv + m * 64;
  const float* ah = fc1o + (size_t)m * 512;
  float acc = 0.f;
#pragma unroll 4
  for (int k = 0; k < 64; k += 4) {
    float4 a = *(const float4*)(aq + k);
    float4 ww = *(const float4*)(wr + k);
    acc += a.x * ww.x + a.y * ww.y + a.z * ww.z + a.w * ww.w;
  }
#pragma unroll 4
  for (int k = 0; k < 500; k += 4) {
    float4 a = *(const float4*)(ah + k);
    float4 ww = *(const float4*)(wr + 64 + k);
    acc += a.x * ww.x + a.y * ww.y + a.z * ww.z + a.w * ww.w;
  }
  out[m * 512 + n] = fmaxf(acc + bias[n], 0.f);
}

__global__ __launch_bounds__(256) void fc3_kernel(const float* __restrict__ qv,
                                                  const float* __restrict__ fc2o,
                                                  const float* __restrict__ w,
                                                  const float* __restrict__ bias,
                                                  float* __restrict__ out) {
  int tid = threadIdx.x;
  int m = tid >> 1, n = tid & 1;
  const float* wr = w + (size_t)n * 564;
  const float* aq = qv + m * 64;
  const float* ah = fc2o + (size_t)m * 512;
  float acc = 0.f;
#pragma unroll 4
  for (int k = 0; k < 64; k += 4) {
    float4 a = *(const float4*)(aq + k);
    float4 ww = *(const float4*)(wr + k);
    acc += a.x * ww.x + a.y * ww.y + a.z * ww.z + a.w * ww.w;
  }
#pragma unroll 4
  for (int k = 0; k < 500; k += 4) {
    float4 a = *(const float4*)(ah + k);
    float4 ww = *(const float4*)(wr + 64 + k);
    acc += a.x * ww.x + a.y * ww.y + a.z * ww.z + a.w * ww.w;
  }
  out[m * 2 + n] = acc + bias[n];
}

// ----------------------------------------------------------- launcher ------
extern "C" void kernel_launch(void* const* d_in, const int* in_sizes, int n_in,
                              void* d_out, int out_size, void* d_ws, size_t ws_size,
                              hipStream_t stream) {
  (void)in_sizes; (void)n_in; (void)out_size; (void)ws_size;
  const float* x      = (const float*)d_in[0];
  const float* qv     = (const float*)d_in[1];
  const float* basis  = (const float*)d_in[2];
  const float* c1aw   = (const float*)d_in[3];
  const float* c1ab   = (const float*)d_in[4];
  const float* c1bw   = (const float*)d_in[5];
  const float* c1bb   = (const float*)d_in[6];
  const float* c2aw   = (const float*)d_in[7];
  const float* c2ab   = (const float*)d_in[8];
  const float* c3aw   = (const float*)d_in[9];
  const float* c3ab   = (const float*)d_in[10];
  const float* bn1a_s = (const float*)d_in[11];
  const float* bn1a_b = (const float*)d_in[12];
  const float* bn1a_m = (const float*)d_in[13];
  const float* bn1a_v = (const float*)d_in[14];
  const float* bn1b_s = (const float*)d_in[15];
  const float* bn1b_b = (const float*)d_in[16];
  const float* bn1b_m = (const float*)d_in[17];
  const float* bn1b_v = (const float*)d_in[18];
  const float* bn2a_s = (const float*)d_in[19];
  const float* bn2a_b = (const float*)d_in[20];
  const float* bn2a_m = (const float*)d_in[21];
  const float* bn2a_v = (const float*)d_in[22];
  const float* bn3a_s = (const float*)d_in[23];
  const float* bn3a_b = (const float*)d_in[24];
  const float* bn3a_m = (const float*)d_in[25];
  const float* bn3a_v = (const float*)d_in[26];
  const float* fc1w   = (const float*)d_in[27];
  const float* fc1b   = (const float*)d_in[28];
  const float* fc2w   = (const float*)d_in[29];
  const float* fc2b   = (const float*)d_in[30];
  const float* fc3w   = (const float*)d_in[31];
  const float* fc3b   = (const float*)d_in[32];

  // ---- workspace layout (float units), peak ~33.84M floats = 135 MB ----
  float* ws = (float*)d_ws;
  float* feat = ws;                        //   983,040
  float* p1   = ws + 1000000;              // 15,728,640 -> 16,728,640
  float* dct  = ws + 16800000;             //  8,388,608 (dead before a1c)
  float* a1c  = ws + 16800000;             //  7,864,320
  float* a2c  = ws + 25200000;             //  7,864,320 -> 33,064,320
  float* a3c  = ws + 16800000;             //  7,864,320 (phase conv2)
  float* p2   = ws + 25200000;             //  7,864,320
  float* a4c  = ws + 16800000;             //  7,864,320 (phase conv3)
  float* p3   = ws;                        //  3,932,160 (feat/p1 dead)
  float* f1p  = ws + 4000000;              //  4,194,304
  float* f1o  = ws + 8200000;              //     65,536
  float* f2o  = ws + 8270000;              //     65,536
  _Float16* wt1b = (_Float16*)(ws + 33100000);  // 122,880 halves
  _Float16* wt2a = (_Float16*)(ws + 33200000);  // 245,760 halves
  _Float16* wt3a = (_Float16*)(ws + 33330000);  // 983,040 halves
  float* sc1b = ws + 33830000; float* sh1b = ws + 33830100;
  float* sc2a = ws + 33830200; float* sh2a = ws + 33830400;
  float* sc3a = ws + 33830600; float* sh3a = ws + 33831000;  // peak ~33,831,256

  // ---- prep: weight transpose (f16) + BN fold ----
  wtrans<64, 64><<<480, 256, 0, stream>>>(c1bw, wt1b);
  wtrans<64, 128><<<960, 256, 0, stream>>>(c2aw, wt2a);
  wtrans<128, 256><<<3840, 256, 0, stream>>>(c3aw, wt3a);
  bnprep<<<1, 256, 0, stream>>>(c1bb, bn1b_s, bn1b_b, bn1b_m, bn1b_v, sc1b, sh1b, 64);
  bnprep<<<1, 256, 0, stream>>>(c2ab, bn2a_s, bn2a_b, bn2a_m, bn2a_v, sc2a, sh2a, 128);
  bnprep<<<1, 256, 0, stream>>>(c3ab, bn3a_s, bn3a_b, bn3a_m, bn3a_v, sc3a, sh3a, 256);

  dct_kernel<<<512, 256, 0, stream>>>(x, basis, dct);
  hist_kernel<<<128 * 64, 256, 0, stream>>>(dct, feat);

  // ---- conv1a (fp32 direct) + conv1b (MFMA) + pool1, 8 chunks of 16 ----
  for (int c = 0; c < 8; ++c) {
    const float* fin = feat + (size_t)c * 16 * 120 * 64;
    float* pout = p1 + (size_t)c * 16 * 64 * 60 * 32;
    conv5_bn_relu<1, 64, 120, 64, 1, 4, 8><<<16 * 2 * 15, 256, 0, stream>>>(
        fin, c1aw, c1ab, bn1a_s, bn1a_b, bn1a_m, bn1a_v, a1c);
    conv5_mfma<64, 64, 120, 64, 64><<<16 * 15 * 1, 256, 0, stream>>>(
        a1c, wt1b, sc1b, sh1b, a2c);
    maxpool2<16, 64, 120, 64><<<1920, 256, 0, stream>>>(a2c, pout);
  }

  // ---- conv2a (MFMA) + pool2, 4 chunks of 32 ----
  for (int c = 0; c < 4; ++c) {
    const float* pin = p1 + (size_t)c * 32 * 64 * 60 * 32;
    float* pout = p2 + (size_t)c * 32 * 128 * 30 * 16;
    conv5_mfma<64, 128, 60, 32, 128><<<32 * 8 * 1, 256, 0, stream>>>(
        pin, wt2a, sc2a, sh2a, a3c);
    maxpool2<32, 128, 60, 32><<<1920, 256, 0, stream>>>(a3c, pout);
  }

  // ---- conv3a (MFMA) + pool3, 2 chunks of 64 ----
  for (int c = 0; c < 2; ++c) {
    const float* pin = p2 + (size_t)c * 64 * 128 * 30 * 16;
    float* pout = p3 + (size_t)c * 64 * 256 * 15 * 8;
    conv5_mfma<128, 256, 30, 16, 128><<<64 * 2 * 2, 256, 0, stream>>>(
        pin, wt3a, sc3a, sh3a, a4c);
    maxpool2<64, 256, 30, 16><<<1920, 256, 0, stream>>>(a4c, pout);
  }

  fc1_partial<<<4 * 64, 256, 0, stream>>>(qv, p3, fc1w, f1p);
  fc1_reduce<<<250, 256, 0, stream>>>(f1p, fc1b, f1o);
  fc2_kernel<<<250, 256, 0, stream>>>(qv, f1o, fc2w, fc2b, f2o);
  fc3_kernel<<<1, 256, 0, stream>>>(qv, f2o, fc3w, fc3b, (float*)d_out);
}

// Round 4
// 1049.125 us; speedup vs baseline: 5.7917x; 2.2751x over previous
//
#include <hip/hip_runtime.h>

// ============================================================================
// Djpegnet round 4.
//  - Activations between convs: channel-grouped f16  [img][c/8][h][w][8ci]
//    -> conv MFMA B-staging = contiguous half8 copies (no transpose, no
//    scalar loads); pools are half8-vectorized; HBM traffic halved.
//  - conv3a emits NCHW f16 so p3 flat order == reference k-order for fc1.
//  - fc1 -> f16 MFMA split-K (KS=120, kc=64): A=fc1_w (M=512 pad), B=acts
//    (N=128 imgs). W cvt fp32->f16 in-register during coalesced staging
//    (read exactly once); fp32 partials + deterministic reduce.
//  - conv2a/conv3a full-batch (grids 1024/512); conv1 in 4x32-img chunks
//    (conv1b grid 480). Peak workspace ~117 MB.
// ============================================================================

typedef _Float16 half8 __attribute__((ext_vector_type(8)));
typedef _Float16 half4 __attribute__((ext_vector_type(4)));
typedef float f32x16 __attribute__((ext_vector_type(16)));

// ---------------------------------------------------------------- DCT ------
__global__ __launch_bounds__(256) void dct_kernel(const float* __restrict__ x,
                                                  const float* __restrict__ basis,
                                                  float* __restrict__ dct) {
  __shared__ __align__(16) float Bm[64];
  int tid = threadIdx.x;
  if (tid < 64) {
    int u = tid >> 3, xx = tid & 7;
    Bm[tid] = basis[(u * 8) * 64 + xx * 8] * 2.8284271247461903f;
  }
  __syncthreads();
  int gid = blockIdx.x * 256 + tid;
  int b = gid >> 10, blk = gid & 1023;
  int bi = blk >> 5, bj = blk & 31;
  const float* xp = x + (size_t)b * 65536 + (bi * 8) * 256 + bj * 8;
  float X[64];
#pragma unroll
  for (int r = 0; r < 8; ++r) {
    float4 p = *(const float4*)(xp + r * 256);
    float4 q = *(const float4*)(xp + r * 256 + 4);
    X[r * 8 + 0] = p.x; X[r * 8 + 1] = p.y; X[r * 8 + 2] = p.z; X[r * 8 + 3] = p.w;
    X[r * 8 + 4] = q.x; X[r * 8 + 5] = q.y; X[r * 8 + 6] = q.z; X[r * 8 + 7] = q.w;
  }
  float T[64];
#pragma unroll
  for (int u = 0; u < 8; ++u) {
    float t[8] = {0.f, 0.f, 0.f, 0.f, 0.f, 0.f, 0.f, 0.f};
#pragma unroll
    for (int xx = 0; xx < 8; ++xx) {
      float bm = Bm[u * 8 + xx];
#pragma unroll
      for (int y = 0; y < 8; ++y) t[y] += bm * X[xx * 8 + y];
    }
#pragma unroll
    for (int y = 0; y < 8; ++y) T[u * 8 + y] = t[y];
  }
  float* op = dct + (size_t)b * 65536 + bi * 32 + bj;
#pragma unroll
  for (int v = 0; v < 8; ++v) {
    float dc[8] = {0.f, 0.f, 0.f, 0.f, 0.f, 0.f, 0.f, 0.f};
#pragma unroll
    for (int y = 0; y < 8; ++y) {
      float bm = Bm[v * 8 + y];
#pragma unroll
      for (int u = 0; u < 8; ++u) dc[u] += bm * T[u * 8 + y];
    }
#pragma unroll
    for (int u = 0; u < 8; ++u) op[(u * 8 + v) * 1024] = dc[u];
  }
}

// ---------------------------------------------------- soft histogram -------
__global__ __launch_bounds__(256) void hist_kernel(const float* __restrict__ dct,
                                                   float* __restrict__ feat) {
  __shared__ __align__(16) float h[16 * 121];
  int tid = threadIdx.x;
  for (int i = tid; i < 16 * 121; i += 256) h[i] = 0.f;
  __syncthreads();
  int b = blockIdx.x >> 6, c = blockIdx.x & 63;
  const float* dp = dct + (size_t)(b * 64 + c) * 1024;
  float* hc = h + (tid & 15) * 121;
  float4 v4 = ((const float4*)dp)[tid];
  float vals[4] = {v4.x, v4.y, v4.z, v4.w};
#pragma unroll
  for (int i = 0; i < 4; ++i) {
    float d = vals[i];
    float fl = floorf(d);
    float t0 = d - fl;
    int k = (int)fl + 60;
    if (t0 >= 2e-5f && t0 <= 1.f - 1.2e-4f) {
      if (k >= 0 && k < 120) atomicAdd(hc + k, 1.0f);
    } else {
      float s0 = 1.f / (1.f + expf(-1e6f * t0));
      float s1 = 1.f / (1.f + expf(1e6f * (1.f - t0)));
      if (k >= 1 && k <= 120) atomicAdd(hc + k - 1, 1.f - s0);
      if (k >= 0 && k < 120)  atomicAdd(hc + k, s0 - s1);
      if (k >= -1 && k < 119) atomicAdd(hc + k + 1, s1);
    }
  }
  __syncthreads();
  for (int f = tid; f < 120; f += 256) {
    float s = 0.f;
#pragma unroll
    for (int l = 0; l < 16; ++l) s += h[l * 121 + f];
    feat[((size_t)b * 120 + f) * 64 + c] = s * (1.f / 1024.f);
  }
}

// ---------------------------------------- weight transpose + BN folding ----
template <int CI, int CO>
__global__ __launch_bounds__(256) void wtrans(const float* __restrict__ w,
                                              _Float16* __restrict__ wt) {
  int i = blockIdx.x * 256 + threadIdx.x;
  if (i >= 30 * CO * CI) return;
  int ci = i % CI;
  int t = i / CI;
  int co = t % CO;
  int k = t / CO;
  int kh = k / 6, kw = k % 6;
  float v = (kw < 5) ? w[((size_t)co * CI + ci) * 25 + kh * 5 + kw] : 0.f;
  wt[i] = (_Float16)v;
}

__global__ __launch_bounds__(256) void bnprep(const float* __restrict__ cb,
                                              const float* __restrict__ s,
                                              const float* __restrict__ b,
                                              const float* __restrict__ m,
                                              const float* __restrict__ v,
                                              float* __restrict__ scale,
                                              float* __restrict__ shift, int n) {
  int i = threadIdx.x;
  if (i < n) {
    float inv = s[i] * rsqrtf(v[i] + 1e-5f);
    scale[i] = inv;
    shift[i] = (cb[i] - m[i]) * inv + b[i];
  }
}

// -------------------------- conv1a: fp32 direct, out grouped-NHWC f16 ------
// grid = imgs*2*15; block 256 = 8cog x 4wg x 8hh.
__global__ __launch_bounds__(256) void conv1a_f16(
    const float* __restrict__ in, const float* __restrict__ wts,
    const float* __restrict__ cb, const float* __restrict__ s_,
    const float* __restrict__ b_, const float* __restrict__ m_,
    const float* __restrict__ v_, _Float16* __restrict__ out) {
  __shared__ __align__(16) float wl[5 * 8 * 20];
  __shared__ __align__(16) float il[12 * 68];
  int tid = threadIdx.x, bid = blockIdx.x;
  int img = bid / 30;
  int r = bid % 30;
  int cob = r / 15;
  int h0 = (r % 15) * 8;
  int cog = tid & 7, wg = (tid >> 3) & 3, hh = tid >> 5;
  float acc[4][16];
#pragma unroll
  for (int i = 0; i < 4; ++i)
#pragma unroll
    for (int j = 0; j < 16; ++j) acc[i][j] = 0.f;
  for (int idx = tid; idx < 32 * 25; idx += 256) {
    int rr = idx % 25, co = idx / 25;
    float v = wts[(cob * 32 + co) * 25 + rr];
    int kh = rr / 5, kw = rr % 5;
    wl[(kh * 8 + (co >> 2)) * 20 + (co & 3) * 5 + kw] = v;
  }
  for (int idx = tid; idx < 12 * 68; idx += 256) {
    int cc = idx % 68, rr = idx / 68;
    int hy = h0 + rr - 2, wx = cc - 2;
    float v = 0.f;
    if (hy >= 0 && hy < 120 && wx >= 0 && wx < 64)
      v = in[(size_t)img * 7680 + hy * 64 + wx];
    il[idx] = v;
  }
  __syncthreads();
#pragma unroll
  for (int kh = 0; kh < 5; ++kh) {
    const float* ir = &il[(hh + kh) * 68 + wg * 16];
    float iv[20];
#pragma unroll
    for (int i = 0; i < 5; ++i) {
      float4 p = *(const float4*)(ir + i * 4);
      iv[i * 4] = p.x; iv[i * 4 + 1] = p.y; iv[i * 4 + 2] = p.z; iv[i * 4 + 3] = p.w;
    }
    const float* wr = &wl[(kh * 8 + cog) * 20];
    float wv[20];
#pragma unroll
    for (int i = 0; i < 5; ++i) {
      float4 p = *(const float4*)(wr + i * 4);
      wv[i * 4] = p.x; wv[i * 4 + 1] = p.y; wv[i * 4 + 2] = p.z; wv[i * 4 + 3] = p.w;
    }
#pragma unroll
    for (int co = 0; co < 4; ++co)
#pragma unroll
      for (int kw = 0; kw < 5; ++kw) {
        float w1 = wv[co * 5 + kw];
#pragma unroll
        for (int w = 0; w < 16; ++w) acc[co][w] += w1 * iv[w + kw];
      }
  }
  int h = h0 + hh;
  int co0 = cob * 32 + cog * 4;
  float inv[4], bia[4];
#pragma unroll
  for (int i = 0; i < 4; ++i) {
    int c = co0 + i;
    inv[i] = s_[c] * rsqrtf(v_[c] + 1e-5f);
    bia[i] = (cb[c] - m_[c]) * inv[i] + b_[c];
  }
  int g = co0 >> 3, off = co0 & 7;  // off = 0 or 4
  _Float16* op = out + (((size_t)(img * 8 + g) * 120 + h) * 64) * 8 + off;
#pragma unroll
  for (int w = 0; w < 16; ++w) {
    half4 o;
#pragma unroll
    for (int i = 0; i < 4; ++i)
      o[i] = (_Float16)fmaxf(acc[i][w] * inv[i] + bia[i], 0.f);
    *(half4*)&op[(size_t)(wg * 16 + w) * 8] = o;
  }
}

// -------------------------------- MFMA implicit-GEMM 5x5 conv + BN + ReLU --
// Input grouped-NHWC f16 [img][CI/8][H][W][8]; output grouped-NHWC f16 or
// NCHW f16 (conv3a). grid = nimg * TB * NCOB, 4 waves, wave = 64co x 128px.
template <int CI, int CO, int H, int W, int BLK_M, bool OUT_NCHW>
__global__ __launch_bounds__(256, 2) void conv5_mfma(
    const _Float16* __restrict__ in, const _Float16* __restrict__ wt,
    const float* __restrict__ scale, const float* __restrict__ shift,
    _Float16* __restrict__ out) {
  constexpr int NW_M = BLK_M / 64;
  constexpr int NW_N = 4 / NW_M;
  constexpr int BLK_N = NW_N * 128;
  constexpr int ROWS = BLK_N / W;
  constexpr int TB = (H + ROWS - 1) / ROWS;
  constexpr int NCOB = CO / BLK_M;
  constexpr int HR = ROWS + 4;
  constexpr int HC = W + 4;
  constexpr int CIG = CI / 8;
  __shared__ __align__(16) _Float16 Alds[HR * HC * 8 + 8];
  __shared__ __align__(16) _Float16 Wlds[30 * BLK_M * 8];

  int tid = threadIdx.x;
  int bid = blockIdx.x;
  int img = bid / (TB * NCOB);
  int r = bid % (TB * NCOB);
  int tb = r / NCOB;
  int cob = r % NCOB;
  int h0 = tb * ROWS;

  int wid = tid >> 6, l = tid & 63, lo = l & 31, hi = l >> 5;
  int widM = wid / NW_N, widN = wid % NW_N;

  int wbase[2];
#pragma unroll
  for (int mi = 0; mi < 2; ++mi)
    wbase[mi] = (hi * BLK_M + widM * 64 + mi * 32 + lo) * 8;
  int bbase[4], pr_[4], pc_[4];
#pragma unroll
  for (int j = 0; j < 4; ++j) {
    int pix = widN * 128 + j * 32 + lo;
    pr_[j] = pix / W;
    pc_[j] = pix % W;
    bbase[j] = (pr_[j] * HC + pc_[j] + hi) * 8;
  }

  f32x16 acc[2][4];
#pragma unroll
  for (int mi = 0; mi < 2; ++mi)
#pragma unroll
    for (int j = 0; j < 4; ++j) acc[mi][j] = (f32x16){};

#pragma unroll 1
  for (int ci0 = 0; ci0 < CI; ci0 += 8) {
    int cg = ci0 >> 3;
    const _Float16* ing = in + (size_t)(img * CIG + cg) * H * W * 8;
    for (int i = tid; i < HR * HC; i += 256) {
      int rr = i / HC, cc = i % HC;
      int hy = h0 + rr - 2, wx = cc - 2;
      half8 v = {};
      if (hy >= 0 && hy < H && wx >= 0 && wx < W)
        v = *(const half8*)&ing[(size_t)(hy * W + wx) * 8];
      *(half8*)&Alds[i * 8] = v;
    }
    for (int i = tid; i < 30 * BLK_M; i += 256) {
      int k = i / BLK_M, co = i % BLK_M;
      *(half8*)&Wlds[i * 8] =
          *(const half8*)&wt[((size_t)k * CO + cob * BLK_M + co) * CI + ci0];
    }
    __syncthreads();
#pragma unroll
    for (int kh = 0; kh < 5; ++kh) {
#pragma unroll
      for (int kwb = 0; kwb < 3; ++kwb) {
        half8 af[2], bf[4];
#pragma unroll
        for (int mi = 0; mi < 2; ++mi)
          af[mi] = *(const half8*)&Wlds[wbase[mi] + (kh * 6 + 2 * kwb) * BLK_M * 8];
#pragma unroll
        for (int j = 0; j < 4; ++j)
          bf[j] = *(const half8*)&Alds[bbase[j] + (kh * HC + 2 * kwb) * 8];
#pragma unroll
        for (int mi = 0; mi < 2; ++mi)
#pragma unroll
          for (int j = 0; j < 4; ++j)
            acc[mi][j] = __builtin_amdgcn_mfma_f32_32x32x16_f16(
                af[mi], bf[j], acc[mi][j], 0, 0, 0);
      }
    }
    __syncthreads();
  }

  if (!OUT_NCHW) {
    constexpr int CGO = CO / 8;
    int gbase = (cob * BLK_M + widM * 64) >> 3;
#pragma unroll
    for (int mi = 0; mi < 2; ++mi) {
#pragma unroll
      for (int r4 = 0; r4 < 4; ++r4) {
        int g = gbase + mi * 4 + r4;
        int co0 = g * 8 + hi * 4;
        float4 sv = *(const float4*)&scale[co0];
        float4 tv = *(const float4*)&shift[co0];
#pragma unroll
        for (int j = 0; j < 4; ++j) {
          int hy = h0 + pr_[j];
          if (hy < H) {
            half4 o;
            o[0] = (_Float16)fmaxf(acc[mi][j][r4 * 4 + 0] * sv.x + tv.x, 0.f);
            o[1] = (_Float16)fmaxf(acc[mi][j][r4 * 4 + 1] * sv.y + tv.y, 0.f);
            o[2] = (_Float16)fmaxf(acc[mi][j][r4 * 4 + 2] * sv.z + tv.z, 0.f);
            o[3] = (_Float16)fmaxf(acc[mi][j][r4 * 4 + 3] * sv.w + tv.w, 0.f);
            *(half4*)&out[(((size_t)(img * CGO + g) * H + hy) * W + pc_[j]) * 8 +
                          hi * 4] = o;
          }
        }
      }
    }
  } else {
#pragma unroll
    for (int mi = 0; mi < 2; ++mi) {
#pragma unroll
      for (int reg = 0; reg < 16; ++reg) {
        int co = cob * BLK_M + widM * 64 + mi * 32 + (reg & 3) + 8 * (reg >> 2) + 4 * hi;
        float s = scale[co], t = shift[co];
#pragma unroll
        for (int j = 0; j < 4; ++j) {
          int hy = h0 + pr_[j];
          if (hy < H)
            out[((size_t)(img * CO + co) * H + hy) * W + pc_[j]] =
                (_Float16)fmaxf(acc[mi][j][reg] * s + t, 0.f);
        }
      }
    }
  }
}

// ------------------------------------------------- pools (f16, vectorized) -
template <int IMGS, int CG, int H, int W>
__global__ __launch_bounds__(256) void pool_g(const _Float16* __restrict__ in,
                                              _Float16* __restrict__ out) {
  constexpr int OH = H / 2, OW = W / 2;
  int idx = blockIdx.x * 256 + threadIdx.x;
  constexpr int TOTAL = IMGS * CG * OH * OW;
  if (idx >= TOTAL) return;
  int ow = idx % OW;
  int t = idx / OW;
  int oh = t % OH; t /= OH;
  int g = t % CG;
  int img = t / CG;
  const half8* in8 = (const half8*)in;
  size_t base = ((size_t)(img * CG + g) * H + 2 * oh) * W + 2 * ow;
  half8 a = in8[base], b = in8[base + 1], c = in8[base + W], d = in8[base + W + 1];
  half8 o;
#pragma unroll
  for (int i = 0; i < 8; ++i) {
    _Float16 m0 = a[i] > b[i] ? a[i] : b[i];
    _Float16 m1 = c[i] > d[i] ? c[i] : d[i];
    o[i] = m0 > m1 ? m0 : m1;
  }
  ((half8*)out)[((size_t)(img * CG + g) * OH + oh) * OW + ow] = o;
}

// pool for NCHW f16 [128][256][30][16] -> [128][256][15][8]
__global__ __launch_bounds__(256) void pool_nchw(const _Float16* __restrict__ in,
                                                 _Float16* __restrict__ out) {
  int idx = blockIdx.x * 256 + threadIdx.x;
  if (idx >= 128 * 256 * 15) return;
  int oh = idx % 15;
  int t = idx / 15;
  int c = t % 256;
  int img = t / 256;
  const half8* r = (const half8*)(in + ((size_t)(img * 256 + c) * 30 + 2 * oh) * 16);
  half8 x0 = r[0], x1 = r[1], y0 = r[2], y1 = r[3];
  half8 o;
#pragma unroll
  for (int ow = 0; ow < 4; ++ow) {
    _Float16 m0 = x0[2 * ow] > x0[2 * ow + 1] ? x0[2 * ow] : x0[2 * ow + 1];
    _Float16 m1 = y0[2 * ow] > y0[2 * ow + 1] ? y0[2 * ow] : y0[2 * ow + 1];
    o[ow] = m0 > m1 ? m0 : m1;
    _Float16 n0 = x1[2 * ow] > x1[2 * ow + 1] ? x1[2 * ow] : x1[2 * ow + 1];
    _Float16 n1 = y1[2 * ow] > y1[2 * ow + 1] ? y1[2 * ow] : y1[2 * ow + 1];
    o[ow + 4] = n0 > n1 ? n0 : n1;
  }
  ((half8*)out)[((size_t)(img * 256 + c) * 15 + oh)] = o;
}

// --------------------------------------------------- fc1: f16 MFMA split-K -
// A = fc1_w (M=512 pad 500), B = acts (N=128). K=30784 = 481 chunks of 64.
// grid = 120 ks x 2 mt. Block: 4 waves, BLK_M=256. part[ks][n512][img128].
__global__ __launch_bounds__(256, 2) void fc1_mfma(const float* __restrict__ qv,
                                                   const _Float16* __restrict__ p3,
                                                   const float* __restrict__ w,
                                                   float* __restrict__ part) {
  __shared__ __align__(16) _Float16 Wl[8 * 256 * 8];  // [k8][n_loc][8]
  __shared__ __align__(16) _Float16 Bl[8 * 128 * 8];  // [k8][img][8]
  int tid = threadIdx.x;
  int ks = blockIdx.x >> 1, mt = blockIdx.x & 1;
  int wid = tid >> 6, l = tid & 63, lo = l & 31, hi = l >> 5;
  f32x16 acc[2][4];
#pragma unroll
  for (int mi = 0; mi < 2; ++mi)
#pragma unroll
    for (int j = 0; j < 4; ++j) acc[mi][j] = (f32x16){};

#pragma unroll 1
  for (int i5 = 0; i5 < 5; ++i5) {
    int c = ks + 120 * i5;
    if (c > 480) break;
    for (int idx = tid; idx < 2048; idx += 256) {
      int n_loc = idx >> 3, k8 = idx & 7;
      int n = mt * 256 + n_loc;
      half8 v = {};
      if (n < 500) {
        const float* src = w + (size_t)n * 30784 + c * 64 + k8 * 8;
        float4 f0 = *(const float4*)src;
        float4 f1 = *(const float4*)(src + 4);
        v[0] = (_Float16)f0.x; v[1] = (_Float16)f0.y;
        v[2] = (_Float16)f0.z; v[3] = (_Float16)f0.w;
        v[4] = (_Float16)f1.x; v[5] = (_Float16)f1.y;
        v[6] = (_Float16)f1.z; v[7] = (_Float16)f1.w;
      }
      *(half8*)&Wl[(size_t)(k8 * 256 + n_loc) * 8] = v;
    }
    for (int idx = tid; idx < 1024; idx += 256) {
      int img = idx >> 3, k8 = idx & 7;
      half8 v;
      if (c == 0) {
        const float* src = qv + img * 64 + k8 * 8;
        float4 f0 = *(const float4*)src;
        float4 f1 = *(const float4*)(src + 4);
        v[0] = (_Float16)f0.x; v[1] = (_Float16)f0.y;
        v[2] = (_Float16)f0.z; v[3] = (_Float16)f0.w;
        v[4] = (_Float16)f1.x; v[5] = (_Float16)f1.y;
        v[6] = (_Float16)f1.z; v[7] = (_Float16)f1.w;
      } else {
        v = *(const half8*)&p3[(size_t)img * 30720 + (c * 64 - 64) + k8 * 8];
      }
      *(half8*)&Bl[(size_t)(k8 * 128 + img) * 8] = v;
    }
    __syncthreads();
#pragma unroll
    for (int ks16 = 0; ks16 < 4; ++ks16) {
      half8 af[2], bf[4];
#pragma unroll
      for (int mi = 0; mi < 2; ++mi)
        af[mi] = *(const half8*)&Wl[(size_t)((ks16 * 2 + hi) * 256 + wid * 64 +
                                             mi * 32 + lo) * 8];
#pragma unroll
      for (int j = 0; j < 4; ++j)
        bf[j] = *(const half8*)&Bl[(size_t)((ks16 * 2 + hi) * 128 + j * 32 + lo) * 8];
#pragma unroll
      for (int mi = 0; mi < 2; ++mi)
#pragma unroll
        for (int j = 0; j < 4; ++j)
          acc[mi][j] = __builtin_amdgcn_mfma_f32_32x32x16_f16(
              af[mi], bf[j], acc[mi][j], 0, 0, 0);
    }
    __syncthreads();
  }
#pragma unroll
  for (int mi = 0; mi < 2; ++mi)
#pragma unroll
    for (int reg = 0; reg < 16; ++reg) {
      int n = mt * 256 + wid * 64 + mi * 32 + (reg & 3) + 8 * (reg >> 2) + 4 * hi;
#pragma unroll
      for (int j = 0; j < 4; ++j)
        part[((size_t)ks * 512 + n) * 128 + j * 32 + lo] = acc[mi][j][reg];
    }
}

__global__ __launch_bounds__(256) void fc1_reduce(const float* __restrict__ part,
                                                  const float* __restrict__ bias,
                                                  float* __restrict__ out) {
  int idx = blockIdx.x * 256 + threadIdx.x;  // 65536 = 512 n x 128 img
  int img = idx & 127, n = idx >> 7;
  float s = 0.f;
#pragma unroll 8
  for (int ks = 0; ks < 120; ++ks) s += part[((size_t)ks * 512 + n) * 128 + img];
  out[n * 128 + img] = (n < 500) ? fmaxf(s + bias[n], 0.f) : 0.f;
}

// -------------------------------------------------------- fc2 / fc3 --------
// fc1o/fc2o layout: [n][img] fp32 (coalesced across img).
__global__ __launch_bounds__(256) void fc2_kernel(const float* __restrict__ qv,
                                                  const float* __restrict__ fc1o,
                                                  const float* __restrict__ w,
                                                  const float* __restrict__ bias,
                                                  float* __restrict__ out) {
  int idx = blockIdx.x * 256 + threadIdx.x;
  if (idx >= 128 * 500) return;
  int m = idx & 127, n = idx >> 7;
  const float* wr = w + (size_t)n * 564;
  float acc = 0.f;
#pragma unroll 8
  for (int k = 0; k < 64; ++k) acc += qv[m * 64 + k] * wr[k];
#pragma unroll 4
  for (int k = 0; k < 500; ++k) acc += fc1o[k * 128 + m] * wr[64 + k];
  out[n * 128 + m] = fmaxf(acc + bias[n], 0.f);
}

__global__ __launch_bounds__(256) void fc3_kernel(const float* __restrict__ qv,
                                                  const float* __restrict__ fc2o,
                                                  const float* __restrict__ w,
                                                  const float* __restrict__ bias,
                                                  float* __restrict__ out) {
  int tid = threadIdx.x;
  int m = tid >> 1, n = tid & 1;
  const float* wr = w + (size_t)n * 564;
  float acc = 0.f;
#pragma unroll 8
  for (int k = 0; k < 64; ++k) acc += qv[m * 64 + k] * wr[k];
#pragma unroll 4
  for (int k = 0; k < 500; ++k) acc += fc2o[k * 128 + m] * wr[64 + k];
  out[m * 2 + n] = acc + bias[n];
}

// ----------------------------------------------------------- launcher ------
extern "C" void kernel_launch(void* const* d_in, const int* in_sizes, int n_in,
                              void* d_out, int out_size, void* d_ws, size_t ws_size,
                              hipStream_t stream) {
  (void)in_sizes; (void)n_in; (void)out_size; (void)ws_size;
  const float* x      = (const float*)d_in[0];
  const float* qv     = (const float*)d_in[1];
  const float* basis  = (const float*)d_in[2];
  const float* c1aw   = (const float*)d_in[3];
  const float* c1ab   = (const float*)d_in[4];
  const float* c1bw   = (const float*)d_in[5];
  const float* c1bb   = (const float*)d_in[6];
  const float* c2aw   = (const float*)d_in[7];
  const float* c2ab   = (const float*)d_in[8];
  const float* c3aw   = (const float*)d_in[9];
  const float* c3ab   = (const float*)d_in[10];
  const float* bn1a_s = (const float*)d_in[11];
  const float* bn1a_b = (const float*)d_in[12];
  const float* bn1a_m = (const float*)d_in[13];
  const float* bn1a_v = (const float*)d_in[14];
  const float* bn1b_s = (const float*)d_in[15];
  const float* bn1b_b = (const float*)d_in[16];
  const float* bn1b_m = (const float*)d_in[17];
  const float* bn1b_v = (const float*)d_in[18];
  const float* bn2a_s = (const float*)d_in[19];
  const float* bn2a_b = (const float*)d_in[20];
  const float* bn2a_m = (const float*)d_in[21];
  const float* bn2a_v = (const float*)d_in[22];
  const float* bn3a_s = (const float*)d_in[23];
  const float* bn3a_b = (const float*)d_in[24];
  const float* bn3a_m = (const float*)d_in[25];
  const float* bn3a_v = (const float*)d_in[26];
  const float* fc1w   = (const float*)d_in[27];
  const float* fc1b   = (const float*)d_in[28];
  const float* fc2w   = (const float*)d_in[29];
  const float* fc2b   = (const float*)d_in[30];
  const float* fc3w   = (const float*)d_in[31];
  const float* fc3b   = (const float*)d_in[32];

  // ---- workspace (fl units), peak ~29.3M fl = 117 MB ----
  float* ws = (float*)d_ws;
  float* feat = ws;                                   //   983,040
  _Float16* wt1b = (_Float16*)(ws + 1000000);         //   122,880 h
  _Float16* wt2a = (_Float16*)(ws + 1070000);         //   245,760 h
  _Float16* wt3a = (_Float16*)(ws + 1200000);         //   983,040 h
  float* sc1b = ws + 1700000; float* sh1b = ws + 1700100;
  float* sc2a = ws + 1700200; float* sh2a = ws + 1700400;
  float* sc3a = ws + 1700600; float* sh3a = ws + 1701000;
  _Float16* p1 = (_Float16*)(ws + 1710000);           // 15,728,640 h (full)
  float* S = ws + 9600000;
  float* dct     = S;                                 //  8,388,608 (dead early)
  _Float16* a1c  = (_Float16*)S;                      // 15,728,640 h (chunk)
  _Float16* a2c  = (_Float16*)(S + 8000000);          // 15,728,640 h (chunk)
  _Float16* a3   = (_Float16*)S;                      // 31,457,280 h (full)
  _Float16* p2   = (_Float16*)(S + 15750000);         //  7,864,320 h (full)
  _Float16* a4   = (_Float16*)S;                      // 15,728,640 h (full, NCHW)
  _Float16* p3   = (_Float16*)(ws + 1710000);         //  3,932,160 h (p1 slot)
  float* f1p  = S + 8000000;                          //  7,864,320 fl
  float* f1o  = S;                                    //     65,536
  float* f2o  = S + 100000;                           //     65,536

  wtrans<64, 64><<<480, 256, 0, stream>>>(c1bw, wt1b);
  wtrans<64, 128><<<960, 256, 0, stream>>>(c2aw, wt2a);
  wtrans<128, 256><<<3840, 256, 0, stream>>>(c3aw, wt3a);
  bnprep<<<1, 256, 0, stream>>>(c1bb, bn1b_s, bn1b_b, bn1b_m, bn1b_v, sc1b, sh1b, 64);
  bnprep<<<1, 256, 0, stream>>>(c2ab, bn2a_s, bn2a_b, bn2a_m, bn2a_v, sc2a, sh2a, 128);
  bnprep<<<1, 256, 0, stream>>>(c3ab, bn3a_s, bn3a_b, bn3a_m, bn3a_v, sc3a, sh3a, 256);

  dct_kernel<<<512, 256, 0, stream>>>(x, basis, dct);
  hist_kernel<<<128 * 64, 256, 0, stream>>>(dct, feat);

  // ---- conv1a + conv1b(MFMA) + pool1: 4 chunks of 32 images ----
  for (int c = 0; c < 4; ++c) {
    const float* fin = feat + (size_t)c * 32 * 120 * 64;
    _Float16* pout = p1 + (size_t)c * 32 * 8 * 60 * 32 * 8;
    conv1a_f16<<<32 * 30, 256, 0, stream>>>(fin, c1aw, c1ab, bn1a_s, bn1a_b,
                                            bn1a_m, bn1a_v, a1c);
    conv5_mfma<64, 64, 120, 64, 64, false><<<32 * 15, 256, 0, stream>>>(
        a1c, wt1b, sc1b, sh1b, a2c);
    pool_g<32, 8, 120, 64><<<1920, 256, 0, stream>>>(a2c, pout);
  }

  // ---- conv2a (full batch) + pool2 ----
  conv5_mfma<64, 128, 60, 32, 128, false><<<128 * 8, 256, 0, stream>>>(
      p1, wt2a, sc2a, sh2a, a3);
  pool_g<128, 16, 60, 32><<<3840, 256, 0, stream>>>(a3, p2);

  // ---- conv3a (full batch, NCHW out) + pool3 ----
  conv5_mfma<128, 256, 30, 16, 128, true><<<128 * 2 * 2, 256, 0, stream>>>(
      p2, wt3a, sc3a, sh3a, a4);
  pool_nchw<<<1920, 256, 0, stream>>>(a4, p3);

  // ---- FC stack ----
  fc1_mfma<<<240, 256, 0, stream>>>(qv, p3, fc1w, f1p);
  fc1_reduce<<<256, 256, 0, stream>>>(f1p, fc1b, f1o);
  fc2_kernel<<<250, 256, 0, stream>>>(qv, f1o, fc2w, fc2b, f2o);
  fc3_kernel<<<1, 256, 0, stream>>>(qv, f2o, fc3w, fc3b, (float*)d_out);
}

// Round 5
// 865.997 us; speedup vs baseline: 7.0165x; 1.2115x over previous
//
#include <hip/hip_runtime.h>

// ============================================================================
// Djpegnet round 5.
//  - conv5_mfma: weight staging via __builtin_amdgcn_global_load_lds (16B,
//    async direct-to-LDS; m93->m97-style win). Weights re-blocked to
//    [ci/8][k30][co][8] so staging is a flat memcpy. A-tile stays on the
//    VGPR path (needs halo zero-fill), loads issued before the W-async so
//    in-order vmcnt retires A first.
//  - Alds pad slack zeroed once (was uninitialized LDS under zero weights).
//  - fc1 split-K doubled: 240 K-splits x 2 N-tiles = 480 blocks.
//  - Everything else as round 4 (grouped-f16 activations, conv3a NCHW out,
//    chunked conv1, fused BN).  Peak workspace ~117 MB (proven <=135 MB).
// ============================================================================

typedef _Float16 half8 __attribute__((ext_vector_type(8)));
typedef _Float16 half4 __attribute__((ext_vector_type(4)));
typedef float f32x16 __attribute__((ext_vector_type(16)));

__device__ __forceinline__ void async_copy16(const void* g, void* l) {
  __builtin_amdgcn_global_load_lds(
      (__attribute__((address_space(1))) void*)g,
      (__attribute__((address_space(3))) void*)l, 16, 0, 0);
}

// ---------------------------------------------------------------- DCT ------
__global__ __launch_bounds__(256) void dct_kernel(const float* __restrict__ x,
                                                  const float* __restrict__ basis,
                                                  float* __restrict__ dct) {
  __shared__ __align__(16) float Bm[64];
  int tid = threadIdx.x;
  if (tid < 64) {
    int u = tid >> 3, xx = tid & 7;
    Bm[tid] = basis[(u * 8) * 64 + xx * 8] * 2.8284271247461903f;
  }
  __syncthreads();
  int gid = blockIdx.x * 256 + tid;
  int b = gid >> 10, blk = gid & 1023;
  int bi = blk >> 5, bj = blk & 31;
  const float* xp = x + (size_t)b * 65536 + (bi * 8) * 256 + bj * 8;
  float X[64];
#pragma unroll
  for (int r = 0; r < 8; ++r) {
    float4 p = *(const float4*)(xp + r * 256);
    float4 q = *(const float4*)(xp + r * 256 + 4);
    X[r * 8 + 0] = p.x; X[r * 8 + 1] = p.y; X[r * 8 + 2] = p.z; X[r * 8 + 3] = p.w;
    X[r * 8 + 4] = q.x; X[r * 8 + 5] = q.y; X[r * 8 + 6] = q.z; X[r * 8 + 7] = q.w;
  }
  float T[64];
#pragma unroll
  for (int u = 0; u < 8; ++u) {
    float t[8] = {0.f, 0.f, 0.f, 0.f, 0.f, 0.f, 0.f, 0.f};
#pragma unroll
    for (int xx = 0; xx < 8; ++xx) {
      float bm = Bm[u * 8 + xx];
#pragma unroll
      for (int y = 0; y < 8; ++y) t[y] += bm * X[xx * 8 + y];
    }
#pragma unroll
    for (int y = 0; y < 8; ++y) T[u * 8 + y] = t[y];
  }
  float* op = dct + (size_t)b * 65536 + bi * 32 + bj;
#pragma unroll
  for (int v = 0; v < 8; ++v) {
    float dc[8] = {0.f, 0.f, 0.f, 0.f, 0.f, 0.f, 0.f, 0.f};
#pragma unroll
    for (int y = 0; y < 8; ++y) {
      float bm = Bm[v * 8 + y];
#pragma unroll
      for (int u = 0; u < 8; ++u) dc[u] += bm * T[u * 8 + y];
    }
#pragma unroll
    for (int u = 0; u < 8; ++u) op[(u * 8 + v) * 1024] = dc[u];
  }
}

// ---------------------------------------------------- soft histogram -------
__global__ __launch_bounds__(256) void hist_kernel(const float* __restrict__ dct,
                                                   float* __restrict__ feat) {
  __shared__ __align__(16) float h[16 * 121];
  int tid = threadIdx.x;
  for (int i = tid; i < 16 * 121; i += 256) h[i] = 0.f;
  __syncthreads();
  int b = blockIdx.x >> 6, c = blockIdx.x & 63;
  const float* dp = dct + (size_t)(b * 64 + c) * 1024;
  float* hc = h + (tid & 15) * 121;
  float4 v4 = ((const float4*)dp)[tid];
  float vals[4] = {v4.x, v4.y, v4.z, v4.w};
#pragma unroll
  for (int i = 0; i < 4; ++i) {
    float d = vals[i];
    float fl = floorf(d);
    float t0 = d - fl;
    int k = (int)fl + 60;
    if (t0 >= 2e-5f && t0 <= 1.f - 1.2e-4f) {
      if (k >= 0 && k < 120) atomicAdd(hc + k, 1.0f);
    } else {
      float s0 = 1.f / (1.f + expf(-1e6f * t0));
      float s1 = 1.f / (1.f + expf(1e6f * (1.f - t0)));
      if (k >= 1 && k <= 120) atomicAdd(hc + k - 1, 1.f - s0);
      if (k >= 0 && k < 120)  atomicAdd(hc + k, s0 - s1);
      if (k >= -1 && k < 119) atomicAdd(hc + k + 1, s1);
    }
  }
  __syncthreads();
  for (int f = tid; f < 120; f += 256) {
    float s = 0.f;
#pragma unroll
    for (int l = 0; l < 16; ++l) s += h[l * 121 + f];
    feat[((size_t)b * 120 + f) * 64 + c] = s * (1.f / 1024.f);
  }
}

// ---------------------------------------- weight transpose + BN folding ----
// wt layout: [cg][k30][co][8ci], cg = ci/8, k30 = kh*6+kw (kw==5 zeroed).
template <int CI, int CO>
__global__ __launch_bounds__(256) void wtrans(const float* __restrict__ w,
                                              _Float16* __restrict__ wt) {
  int i = blockIdx.x * 256 + threadIdx.x;
  if (i >= (CI / 8) * 30 * CO * 8) return;
  int c8 = i & 7;
  int t = i >> 3;
  int co = t % CO; t /= CO;
  int k = t % 30;
  int cg = t / 30;
  int ci = cg * 8 + c8;
  int kh = k / 6, kw = k % 6;
  float v = (kw < 5) ? w[((size_t)co * CI + ci) * 25 + kh * 5 + kw] : 0.f;
  wt[i] = (_Float16)v;
}

__global__ __launch_bounds__(256) void bnprep(const float* __restrict__ cb,
                                              const float* __restrict__ s,
                                              const float* __restrict__ b,
                                              const float* __restrict__ m,
                                              const float* __restrict__ v,
                                              float* __restrict__ scale,
                                              float* __restrict__ shift, int n) {
  int i = threadIdx.x;
  if (i < n) {
    float inv = s[i] * rsqrtf(v[i] + 1e-5f);
    scale[i] = inv;
    shift[i] = (cb[i] - m[i]) * inv + b[i];
  }
}

// -------------------------- conv1a: fp32 direct, out grouped-NHWC f16 ------
__global__ __launch_bounds__(256) void conv1a_f16(
    const float* __restrict__ in, const float* __restrict__ wts,
    const float* __restrict__ cb, const float* __restrict__ s_,
    const float* __restrict__ b_, const float* __restrict__ m_,
    const float* __restrict__ v_, _Float16* __restrict__ out) {
  __shared__ __align__(16) float wl[5 * 8 * 20];
  __shared__ __align__(16) float il[12 * 68];
  int tid = threadIdx.x, bid = blockIdx.x;
  int img = bid / 30;
  int r = bid % 30;
  int cob = r / 15;
  int h0 = (r % 15) * 8;
  int cog = tid & 7, wg = (tid >> 3) & 3, hh = tid >> 5;
  float acc[4][16];
#pragma unroll
  for (int i = 0; i < 4; ++i)
#pragma unroll
    for (int j = 0; j < 16; ++j) acc[i][j] = 0.f;
  for (int idx = tid; idx < 32 * 25; idx += 256) {
    int rr = idx % 25, co = idx / 25;
    float v = wts[(cob * 32 + co) * 25 + rr];
    int kh = rr / 5, kw = rr % 5;
    wl[(kh * 8 + (co >> 2)) * 20 + (co & 3) * 5 + kw] = v;
  }
  for (int idx = tid; idx < 12 * 68; idx += 256) {
    int cc = idx % 68, rr = idx / 68;
    int hy = h0 + rr - 2, wx = cc - 2;
    float v = 0.f;
    if (hy >= 0 && hy < 120 && wx >= 0 && wx < 64)
      v = in[(size_t)img * 7680 + hy * 64 + wx];
    il[idx] = v;
  }
  __syncthreads();
#pragma unroll
  for (int kh = 0; kh < 5; ++kh) {
    const float* ir = &il[(hh + kh) * 68 + wg * 16];
    float iv[20];
#pragma unroll
    for (int i = 0; i < 5; ++i) {
      float4 p = *(const float4*)(ir + i * 4);
      iv[i * 4] = p.x; iv[i * 4 + 1] = p.y; iv[i * 4 + 2] = p.z; iv[i * 4 + 3] = p.w;
    }
    const float* wr = &wl[(kh * 8 + cog) * 20];
    float wv[20];
#pragma unroll
    for (int i = 0; i < 5; ++i) {
      float4 p = *(const float4*)(wr + i * 4);
      wv[i * 4] = p.x; wv[i * 4 + 1] = p.y; wv[i * 4 + 2] = p.z; wv[i * 4 + 3] = p.w;
    }
#pragma unroll
    for (int co = 0; co < 4; ++co)
#pragma unroll
      for (int kw = 0; kw < 5; ++kw) {
        float w1 = wv[co * 5 + kw];
#pragma unroll
        for (int w = 0; w < 16; ++w) acc[co][w] += w1 * iv[w + kw];
      }
  }
  int h = h0 + hh;
  int co0 = cob * 32 + cog * 4;
  float inv[4], bia[4];
#pragma unroll
  for (int i = 0; i < 4; ++i) {
    int c = co0 + i;
    inv[i] = s_[c] * rsqrtf(v_[c] + 1e-5f);
    bia[i] = (cb[c] - m_[c]) * inv[i] + b_[c];
  }
  int g = co0 >> 3, off = co0 & 7;
  _Float16* op = out + (((size_t)(img * 8 + g) * 120 + h) * 64) * 8 + off;
#pragma unroll
  for (int w = 0; w < 16; ++w) {
    half4 o;
#pragma unroll
    for (int i = 0; i < 4; ++i)
      o[i] = (_Float16)fmaxf(acc[i][w] * inv[i] + bia[i], 0.f);
    *(half4*)&op[(size_t)(wg * 16 + w) * 8] = o;
  }
}

// -------------------------------- MFMA implicit-GEMM 5x5 conv + BN + ReLU --
template <int CI, int CO, int H, int W, int BLK_M, bool OUT_NCHW>
__global__ __launch_bounds__(256, 2) void conv5_mfma(
    const _Float16* __restrict__ in, const _Float16* __restrict__ wt,
    const float* __restrict__ scale, const float* __restrict__ shift,
    _Float16* __restrict__ out) {
  constexpr int NW_M = BLK_M / 64;
  constexpr int NW_N = 4 / NW_M;
  constexpr int BLK_N = NW_N * 128;
  constexpr int ROWS = BLK_N / W;
  constexpr int TB = (H + ROWS - 1) / ROWS;
  constexpr int NCOB = CO / BLK_M;
  constexpr int HR = ROWS + 4;
  constexpr int HC = W + 4;
  constexpr int CIG = CI / 8;
  constexpr int AITER = (HR * HC + 255) / 256;
  constexpr int WBYTES = 30 * BLK_M * 16;
  constexpr int WITER = (WBYTES + 4095) / 4096;
  __shared__ __align__(16) _Float16 Alds[HR * HC * 8 + 8];
  __shared__ __align__(16) _Float16 Wlds[30 * BLK_M * 8];

  int tid = threadIdx.x;
  int bid = blockIdx.x;
  int img = bid / (TB * NCOB);
  int r = bid % (TB * NCOB);
  int tb = r / NCOB;
  int cob = r % NCOB;
  int h0 = tb * ROWS;

  int wid = tid >> 6, l = tid & 63, lo = l & 31, hi = l >> 5;
  int widM = wid / NW_N, widN = wid % NW_N;

  if (tid < 8) Alds[HR * HC * 8 + tid] = (_Float16)0.f;  // zero read-slack

  int wbase[2];
#pragma unroll
  for (int mi = 0; mi < 2; ++mi)
    wbase[mi] = (hi * BLK_M + widM * 64 + mi * 32 + lo) * 8;
  int bbase[4], pr_[4], pc_[4];
#pragma unroll
  for (int j = 0; j < 4; ++j) {
    int pix = widN * 128 + j * 32 + lo;
    pr_[j] = pix / W;
    pc_[j] = pix % W;
    bbase[j] = (pr_[j] * HC + pc_[j] + hi) * 8;
  }

  f32x16 acc[2][4];
#pragma unroll
  for (int mi = 0; mi < 2; ++mi)
#pragma unroll
    for (int j = 0; j < 4; ++j) acc[mi][j] = (f32x16){};

#pragma unroll 1
  for (int ci0 = 0; ci0 < CI; ci0 += 8) {
    int cg = ci0 >> 3;
    const _Float16* ing = in + (size_t)(img * CIG + cg) * H * W * 8;
    // ---- A loads into regs first (oldest in vmcnt queue) ----
    half8 areg[AITER];
#pragma unroll
    for (int it = 0; it < AITER; ++it) {
      int i = tid + it * 256;
      half8 v = {};
      if (i < HR * HC) {
        int rr = i / HC, cc = i % HC;
        int hy = h0 + rr - 2, wx = cc - 2;
        if (hy >= 0 && hy < H && wx >= 0 && wx < W)
          v = *(const half8*)&ing[(size_t)(hy * W + wx) * 8];
      }
      areg[it] = v;
    }
    // ---- W: async direct-to-LDS memcpy ----
    const char* wsrc = (const char*)(wt + ((size_t)cg * 30 * CO + cob * BLK_M) * 8);
#pragma unroll
    for (int rr = 0; rr < WITER; ++rr) {
      int f = rr * 4096 + tid * 16;
      if (f < WBYTES) {
        int row = f / (BLK_M * 16);
        int off = f % (BLK_M * 16);
        async_copy16(wsrc + (size_t)row * (CO * 16) + off,
                     (char*)Wlds + (rr * 4096 + wid * 1024));
      }
    }
    // ---- A writes to LDS ----
#pragma unroll
    for (int it = 0; it < AITER; ++it) {
      int i = tid + it * 256;
      if (i < HR * HC) *(half8*)&Alds[i * 8] = areg[it];
    }
    __syncthreads();
#pragma unroll
    for (int kh = 0; kh < 5; ++kh) {
#pragma unroll
      for (int kwb = 0; kwb < 3; ++kwb) {
        half8 af[2], bf[4];
#pragma unroll
        for (int mi = 0; mi < 2; ++mi)
          af[mi] = *(const half8*)&Wlds[wbase[mi] + (kh * 6 + 2 * kwb) * BLK_M * 8];
#pragma unroll
        for (int j = 0; j < 4; ++j)
          bf[j] = *(const half8*)&Alds[bbase[j] + (kh * HC + 2 * kwb) * 8];
#pragma unroll
        for (int mi = 0; mi < 2; ++mi)
#pragma unroll
          for (int j = 0; j < 4; ++j)
            acc[mi][j] = __builtin_amdgcn_mfma_f32_32x32x16_f16(
                af[mi], bf[j], acc[mi][j], 0, 0, 0);
      }
    }
    __syncthreads();
  }

  if (!OUT_NCHW) {
    constexpr int CGO = CO / 8;
    int gbase = (cob * BLK_M + widM * 64) >> 3;
#pragma unroll
    for (int mi = 0; mi < 2; ++mi) {
#pragma unroll
      for (int r4 = 0; r4 < 4; ++r4) {
        int g = gbase + mi * 4 + r4;
        int co0 = g * 8 + hi * 4;
        float4 sv = *(const float4*)&scale[co0];
        float4 tv = *(const float4*)&shift[co0];
#pragma unroll
        for (int j = 0; j < 4; ++j) {
          int hy = h0 + pr_[j];
          if (hy < H) {
            half4 o;
            o[0] = (_Float16)fmaxf(acc[mi][j][r4 * 4 + 0] * sv.x + tv.x, 0.f);
            o[1] = (_Float16)fmaxf(acc[mi][j][r4 * 4 + 1] * sv.y + tv.y, 0.f);
            o[2] = (_Float16)fmaxf(acc[mi][j][r4 * 4 + 2] * sv.z + tv.z, 0.f);
            o[3] = (_Float16)fmaxf(acc[mi][j][r4 * 4 + 3] * sv.w + tv.w, 0.f);
            *(half4*)&out[(((size_t)(img * CGO + g) * H + hy) * W + pc_[j]) * 8 +
                          hi * 4] = o;
          }
        }
      }
    }
  } else {
#pragma unroll
    for (int mi = 0; mi < 2; ++mi) {
#pragma unroll
      for (int reg = 0; reg < 16; ++reg) {
        int co = cob * BLK_M + widM * 64 + mi * 32 + (reg & 3) + 8 * (reg >> 2) + 4 * hi;
        float s = scale[co], t = shift[co];
#pragma unroll
        for (int j = 0; j < 4; ++j) {
          int hy = h0 + pr_[j];
          if (hy < H)
            out[((size_t)(img * CO + co) * H + hy) * W + pc_[j]] =
                (_Float16)fmaxf(acc[mi][j][reg] * s + t, 0.f);
        }
      }
    }
  }
}

// ------------------------------------------------- pools (f16, vectorized) -
template <int IMGS, int CG, int H, int W>
__global__ __launch_bounds__(256) void pool_g(const _Float16* __restrict__ in,
                                              _Float16* __restrict__ out) {
  constexpr int OH = H / 2, OW = W / 2;
  int idx = blockIdx.x * 256 + threadIdx.x;
  constexpr int TOTAL = IMGS * CG * OH * OW;
  if (idx >= TOTAL) return;
  int ow = idx % OW;
  int t = idx / OW;
  int oh = t % OH; t /= OH;
  int g = t % CG;
  int img = t / CG;
  const half8* in8 = (const half8*)in;
  size_t base = ((size_t)(img * CG + g) * H + 2 * oh) * W + 2 * ow;
  half8 a = in8[base], b = in8[base + 1], c = in8[base + W], d = in8[base + W + 1];
  half8 o;
#pragma unroll
  for (int i = 0; i < 8; ++i) {
    _Float16 m0 = a[i] > b[i] ? a[i] : b[i];
    _Float16 m1 = c[i] > d[i] ? c[i] : d[i];
    o[i] = m0 > m1 ? m0 : m1;
  }
  ((half8*)out)[((size_t)(img * CG + g) * OH + oh) * OW + ow] = o;
}

__global__ __launch_bounds__(256) void pool_nchw(const _Float16* __restrict__ in,
                                                 _Float16* __restrict__ out) {
  int idx = blockIdx.x * 256 + threadIdx.x;
  if (idx >= 128 * 256 * 15) return;
  int oh = idx % 15;
  int t = idx / 15;
  int c = t % 256;
  int img = t / 256;
  const half8* r = (const half8*)(in + ((size_t)(img * 256 + c) * 30 + 2 * oh) * 16);
  half8 x0 = r[0], x1 = r[1], y0 = r[2], y1 = r[3];
  half8 o;
#pragma unroll
  for (int ow = 0; ow < 4; ++ow) {
    _Float16 m0 = x0[2 * ow] > x0[2 * ow + 1] ? x0[2 * ow] : x0[2 * ow + 1];
    _Float16 m1 = y0[2 * ow] > y0[2 * ow + 1] ? y0[2 * ow] : y0[2 * ow + 1];
    o[ow] = m0 > m1 ? m0 : m1;
    _Float16 n0 = x1[2 * ow] > x1[2 * ow + 1] ? x1[2 * ow] : x1[2 * ow + 1];
    _Float16 n1 = y1[2 * ow] > y1[2 * ow + 1] ? y1[2 * ow] : y1[2 * ow + 1];
    o[ow + 4] = n0 > n1 ? n0 : n1;
  }
  ((half8*)out)[((size_t)(img * 256 + c) * 15 + oh)] = o;
}

// --------------------------------------------------- fc1: f16 MFMA split-K -
// 240 K-splits x 2 N-tiles = 480 blocks. part[ks][n512][img128].
__global__ __launch_bounds__(256, 2) void fc1_mfma(const float* __restrict__ qv,
                                                   const _Float16* __restrict__ p3,
                                                   const float* __restrict__ w,
                                                   float* __restrict__ part) {
  __shared__ __align__(16) _Float16 Wl[8 * 256 * 8];  // [k8][n_loc][8]
  __shared__ __align__(16) _Float16 Bl[8 * 128 * 8];  // [k8][img][8]
  int tid = threadIdx.x;
  int ks = blockIdx.x >> 1, mt = blockIdx.x & 1;
  int wid = tid >> 6, l = tid & 63, lo = l & 31, hi = l >> 5;
  f32x16 acc[2][4];
#pragma unroll
  for (int mi = 0; mi < 2; ++mi)
#pragma unroll
    for (int j = 0; j < 4; ++j) acc[mi][j] = (f32x16){};

#pragma unroll 1
  for (int i3 = 0; i3 < 3; ++i3) {
    int c = ks + 240 * i3;
    if (c > 480) break;
    for (int idx = tid; idx < 2048; idx += 256) {
      int n_loc = idx >> 3, k8 = idx & 7;
      int n = mt * 256 + n_loc;
      half8 v = {};
      if (n < 500) {
        const float* src = w + (size_t)n * 30784 + c * 64 + k8 * 8;
        float4 f0 = *(const float4*)src;
        float4 f1 = *(const float4*)(src + 4);
        v[0] = (_Float16)f0.x; v[1] = (_Float16)f0.y;
        v[2] = (_Float16)f0.z; v[3] = (_Float16)f0.w;
        v[4] = (_Float16)f1.x; v[5] = (_Float16)f1.y;
        v[6] = (_Float16)f1.z; v[7] = (_Float16)f1.w;
      }
      *(half8*)&Wl[(size_t)(k8 * 256 + n_loc) * 8] = v;
    }
    for (int idx = tid; idx < 1024; idx += 256) {
      int img = idx >> 3, k8 = idx & 7;
      half8 v;
      if (c == 0) {
        const float* src = qv + img * 64 + k8 * 8;
        float4 f0 = *(const float4*)src;
        float4 f1 = *(const float4*)(src + 4);
        v[0] = (_Float16)f0.x; v[1] = (_Float16)f0.y;
        v[2] = (_Float16)f0.z; v[3] = (_Float16)f0.w;
        v[4] = (_Float16)f1.x; v[5] = (_Float16)f1.y;
        v[6] = (_Float16)f1.z; v[7] = (_Float16)f1.w;
      } else {
        v = *(const half8*)&p3[(size_t)img * 30720 + (c * 64 - 64) + k8 * 8];
      }
      *(half8*)&Bl[(size_t)(k8 * 128 + img) * 8] = v;
    }
    __syncthreads();
#pragma unroll
    for (int ks16 = 0; ks16 < 4; ++ks16) {
      half8 af[2], bf[4];
#pragma unroll
      for (int mi = 0; mi < 2; ++mi)
        af[mi] = *(const half8*)&Wl[(size_t)((ks16 * 2 + hi) * 256 + wid * 64 +
                                             mi * 32 + lo) * 8];
#pragma unroll
      for (int j = 0; j < 4; ++j)
        bf[j] = *(const half8*)&Bl[(size_t)((ks16 * 2 + hi) * 128 + j * 32 + lo) * 8];
#pragma unroll
      for (int mi = 0; mi < 2; ++mi)
#pragma unroll
        for (int j = 0; j < 4; ++j)
          acc[mi][j] = __builtin_amdgcn_mfma_f32_32x32x16_f16(
              af[mi], bf[j], acc[mi][j], 0, 0, 0);
    }
    __syncthreads();
  }
#pragma unroll
  for (int mi = 0; mi < 2; ++mi)
#pragma unroll
    for (int reg = 0; reg < 16; ++reg) {
      int n = mt * 256 + wid * 64 + mi * 32 + (reg & 3) + 8 * (reg >> 2) + 4 * hi;
#pragma unroll
      for (int j = 0; j < 4; ++j)
        part[((size_t)ks * 512 + n) * 128 + j * 32 + lo] = acc[mi][j][reg];
    }
}

__global__ __launch_bounds__(256) void fc1_reduce(const float* __restrict__ part,
                                                  const float* __restrict__ bias,
                                                  float* __restrict__ out) {
  int idx = blockIdx.x * 256 + threadIdx.x;  // 65536 = 512 n x 128 img
  int img = idx & 127, n = idx >> 7;
  float s = 0.f;
#pragma unroll 8
  for (int ks = 0; ks < 240; ++ks) s += part[((size_t)ks * 512 + n) * 128 + img];
  out[n * 128 + img] = (n < 500) ? fmaxf(s + bias[n], 0.f) : 0.f;
}

// -------------------------------------------------------- fc2 / fc3 --------
__global__ __launch_bounds__(256) void fc2_kernel(const float* __restrict__ qv,
                                                  const float* __restrict__ fc1o,
                                                  const float* __restrict__ w,
                                                  const float* __restrict__ bias,
                                                  float* __restrict__ out) {
  int idx = blockIdx.x * 256 + threadIdx.x;
  if (idx >= 128 * 500) return;
  int m = idx & 127, n = idx >> 7;
  const float* wr = w + (size_t)n * 564;
  float acc = 0.f;
#pragma unroll 8
  for (int k = 0; k < 64; ++k) acc += qv[m * 64 + k] * wr[k];
#pragma unroll 4
  for (int k = 0; k < 500; ++k) acc += fc1o[k * 128 + m] * wr[64 + k];
  out[n * 128 + m] = fmaxf(acc + bias[n], 0.f);
}

__global__ __launch_bounds__(256) void fc3_kernel(const float* __restrict__ qv,
                                                  const float* __restrict__ fc2o,
                                                  const float* __restrict__ w,
                                                  const float* __restrict__ bias,
                                                  float* __restrict__ out) {
  int tid = threadIdx.x;
  int m = tid >> 1, n = tid & 1;
  const float* wr = w + (size_t)n * 564;
  float acc = 0.f;
#pragma unroll 8
  for (int k = 0; k < 64; ++k) acc += qv[m * 64 + k] * wr[k];
#pragma unroll 4
  for (int k = 0; k < 500; ++k) acc += fc2o[k * 128 + m] * wr[64 + k];
  out[m * 2 + n] = acc + bias[n];
}

// ----------------------------------------------------------- launcher ------
extern "C" void kernel_launch(void* const* d_in, const int* in_sizes, int n_in,
                              void* d_out, int out_size, void* d_ws, size_t ws_size,
                              hipStream_t stream) {
  (void)in_sizes; (void)n_in; (void)out_size; (void)ws_size;
  const float* x      = (const float*)d_in[0];
  const float* qv     = (const float*)d_in[1];
  const float* basis  = (const float*)d_in[2];
  const float* c1aw   = (const float*)d_in[3];
  const float* c1ab   = (const float*)d_in[4];
  const float* c1bw   = (const float*)d_in[5];
  const float* c1bb   = (const float*)d_in[6];
  const float* c2aw   = (const float*)d_in[7];
  const float* c2ab   = (const float*)d_in[8];
  const float* c3aw   = (const float*)d_in[9];
  const float* c3ab   = (const float*)d_in[10];
  const float* bn1a_s = (const float*)d_in[11];
  const float* bn1a_b = (const float*)d_in[12];
  const float* bn1a_m = (const float*)d_in[13];
  const float* bn1a_v = (const float*)d_in[14];
  const float* bn1b_s = (const float*)d_in[15];
  const float* bn1b_b = (const float*)d_in[16];
  const float* bn1b_m = (const float*)d_in[17];
  const float* bn1b_v = (const float*)d_in[18];
  const float* bn2a_s = (const float*)d_in[19];
  const float* bn2a_b = (const float*)d_in[20];
  const float* bn2a_m = (const float*)d_in[21];
  const float* bn2a_v = (const float*)d_in[22];
  const float* bn3a_s = (const float*)d_in[23];
  const float* bn3a_b = (const float*)d_in[24];
  const float* bn3a_m = (const float*)d_in[25];
  const float* bn3a_v = (const float*)d_in[26];
  const float* fc1w   = (const float*)d_in[27];
  const float* fc1b   = (const float*)d_in[28];
  const float* fc2w   = (const float*)d_in[29];
  const float* fc2b   = (const float*)d_in[30];
  const float* fc3w   = (const float*)d_in[31];
  const float* fc3b   = (const float*)d_in[32];

  // ---- workspace (fl units), peak ~29.3M fl = 117 MB ----
  float* ws = (float*)d_ws;
  float* feat = ws;                                   //   983,040
  _Float16* wt1b = (_Float16*)(ws + 1000000);         //   122,880 h
  _Float16* wt2a = (_Float16*)(ws + 1070000);         //   245,760 h
  _Float16* wt3a = (_Float16*)(ws + 1200000);         //   983,040 h
  float* sc1b = ws + 1700000; float* sh1b = ws + 1700100;
  float* sc2a = ws + 1700200; float* sh2a = ws + 1700400;
  float* sc3a = ws + 1700600; float* sh3a = ws + 1701000;
  _Float16* p1 = (_Float16*)(ws + 1710000);           // 15,728,640 h (full)
  float* S = ws + 9600000;
  float* dct     = S;                                 //  8,388,608 (dead early)
  _Float16* a1c  = (_Float16*)S;                      // 15,728,640 h (chunk)
  _Float16* a2c  = (_Float16*)(S + 8000000);          // 15,728,640 h (chunk)
  _Float16* a3   = (_Float16*)S;                      // 31,457,280 h (full)
  _Float16* p2   = (_Float16*)(S + 15750000);         //  7,864,320 h (full)
  _Float16* a4   = (_Float16*)S;                      // 15,728,640 h (full, NCHW)
  _Float16* p3   = (_Float16*)(ws + 1710000);         //  3,932,160 h (p1 slot)
  float* f1p  = S;                                    // 15,728,640 fl (a4/p2 dead)
  float* f1o  = ws + 25400000;                        //     65,536
  float* f2o  = ws + 25500000;                        //     65,536

  wtrans<64, 64><<<480, 256, 0, stream>>>(c1bw, wt1b);
  wtrans<64, 128><<<960, 256, 0, stream>>>(c2aw, wt2a);
  wtrans<128, 256><<<3840, 256, 0, stream>>>(c3aw, wt3a);
  bnprep<<<1, 256, 0, stream>>>(c1bb, bn1b_s, bn1b_b, bn1b_m, bn1b_v, sc1b, sh1b, 64);
  bnprep<<<1, 256, 0, stream>>>(c2ab, bn2a_s, bn2a_b, bn2a_m, bn2a_v, sc2a, sh2a, 128);
  bnprep<<<1, 256, 0, stream>>>(c3ab, bn3a_s, bn3a_b, bn3a_m, bn3a_v, sc3a, sh3a, 256);

  dct_kernel<<<512, 256, 0, stream>>>(x, basis, dct);
  hist_kernel<<<128 * 64, 256, 0, stream>>>(dct, feat);

  // ---- conv1a + conv1b(MFMA) + pool1: 4 chunks of 32 images ----
  for (int c = 0; c < 4; ++c) {
    const float* fin = feat + (size_t)c * 32 * 120 * 64;
    _Float16* pout = p1 + (size_t)c * 32 * 8 * 60 * 32 * 8;
    conv1a_f16<<<32 * 30, 256, 0, stream>>>(fin, c1aw, c1ab, bn1a_s, bn1a_b,
                                            bn1a_m, bn1a_v, a1c);
    conv5_mfma<64, 64, 120, 64, 64, false><<<32 * 15, 256, 0, stream>>>(
        a1c, wt1b, sc1b, sh1b, a2c);
    pool_g<32, 8, 120, 64><<<1920, 256, 0, stream>>>(a2c, pout);
  }

  // ---- conv2a (full batch) + pool2 ----
  conv5_mfma<64, 128, 60, 32, 128, false><<<128 * 8, 256, 0, stream>>>(
      p1, wt2a, sc2a, sh2a, a3);
  pool_g<128, 16, 60, 32><<<3840, 256, 0, stream>>>(a3, p2);

  // ---- conv3a (full batch, NCHW out) + pool3 ----
  conv5_mfma<128, 256, 30, 16, 128, true><<<128 * 2 * 2, 256, 0, stream>>>(
      p2, wt3a, sc3a, sh3a, a4);
  pool_nchw<<<1920, 256, 0, stream>>>(a4, p3);

  // ---- FC stack ----
  fc1_mfma<<<480, 256, 0, stream>>>(qv, p3, fc1w, f1p);
  fc1_reduce<<<256, 256, 0, stream>>>(f1p, fc1b, f1o);
  fc2_kernel<<<250, 256, 0, stream>>>(qv, f1o, fc2w, fc2b, f2o);
  fc3_kernel<<<1, 256, 0, stream>>>(qv, f2o, fc3w, fc3b, (float*)d_out);
}

// Round 6
// 811.258 us; speedup vs baseline: 7.4899x; 1.0675x over previous
//
#include <hip/hip_runtime.h>

// ============================================================================
// Djpegnet round 6.
//  - conv5_mfma: 512 threads / 8 waves, BLK_N doubled (W-tile amortized over
//    2x MFMA, 16 waves/CU). Maxpool FUSED into epilogue via __shfl_xor
//    (col pair = lane^1; row pair = j-pair in-reg, or lane^16 for W=16).
//    Outputs are pooled directly -> a2/a3/a4 buffers and 3 pool kernels gone.
//  - conv1 stage: 2 chunks of 64 images (a2c eliminated by fusion).
//  - Weight staging stays async global_load_lds 16B (round-5 win).
//  - fc1 f16 MFMA split-K (240x2), fc2/fc3/dct/hist unchanged.
// Peak workspace ~118 MB.
// ============================================================================

typedef _Float16 half8 __attribute__((ext_vector_type(8)));
typedef _Float16 half4 __attribute__((ext_vector_type(4)));
typedef float f32x16 __attribute__((ext_vector_type(16)));

__device__ __forceinline__ void async_copy16(const void* g, void* l) {
  __builtin_amdgcn_global_load_lds(
      (__attribute__((address_space(1))) void*)g,
      (__attribute__((address_space(3))) void*)l, 16, 0, 0);
}

// ---------------------------------------------------------------- DCT ------
__global__ __launch_bounds__(256) void dct_kernel(const float* __restrict__ x,
                                                  const float* __restrict__ basis,
                                                  float* __restrict__ dct) {
  __shared__ __align__(16) float Bm[64];
  int tid = threadIdx.x;
  if (tid < 64) {
    int u = tid >> 3, xx = tid & 7;
    Bm[tid] = basis[(u * 8) * 64 + xx * 8] * 2.8284271247461903f;
  }
  __syncthreads();
  int gid = blockIdx.x * 256 + tid;
  int b = gid >> 10, blk = gid & 1023;
  int bi = blk >> 5, bj = blk & 31;
  const float* xp = x + (size_t)b * 65536 + (bi * 8) * 256 + bj * 8;
  float X[64];
#pragma unroll
  for (int r = 0; r < 8; ++r) {
    float4 p = *(const float4*)(xp + r * 256);
    float4 q = *(const float4*)(xp + r * 256 + 4);
    X[r * 8 + 0] = p.x; X[r * 8 + 1] = p.y; X[r * 8 + 2] = p.z; X[r * 8 + 3] = p.w;
    X[r * 8 + 4] = q.x; X[r * 8 + 5] = q.y; X[r * 8 + 6] = q.z; X[r * 8 + 7] = q.w;
  }
  float T[64];
#pragma unroll
  for (int u = 0; u < 8; ++u) {
    float t[8] = {0.f, 0.f, 0.f, 0.f, 0.f, 0.f, 0.f, 0.f};
#pragma unroll
    for (int xx = 0; xx < 8; ++xx) {
      float bm = Bm[u * 8 + xx];
#pragma unroll
      for (int y = 0; y < 8; ++y) t[y] += bm * X[xx * 8 + y];
    }
#pragma unroll
    for (int y = 0; y < 8; ++y) T[u * 8 + y] = t[y];
  }
  float* op = dct + (size_t)b * 65536 + bi * 32 + bj;
#pragma unroll
  for (int v = 0; v < 8; ++v) {
    float dc[8] = {0.f, 0.f, 0.f, 0.f, 0.f, 0.f, 0.f, 0.f};
#pragma unroll
    for (int y = 0; y < 8; ++y) {
      float bm = Bm[v * 8 + y];
#pragma unroll
      for (int u = 0; u < 8; ++u) dc[u] += bm * T[u * 8 + y];
    }
#pragma unroll
    for (int u = 0; u < 8; ++u) op[(u * 8 + v) * 1024] = dc[u];
  }
}

// ---------------------------------------------------- soft histogram -------
__global__ __launch_bounds__(256) void hist_kernel(const float* __restrict__ dct,
                                                   float* __restrict__ feat) {
  __shared__ __align__(16) float h[16 * 121];
  int tid = threadIdx.x;
  for (int i = tid; i < 16 * 121; i += 256) h[i] = 0.f;
  __syncthreads();
  int b = blockIdx.x >> 6, c = blockIdx.x & 63;
  const float* dp = dct + (size_t)(b * 64 + c) * 1024;
  float* hc = h + (tid & 15) * 121;
  float4 v4 = ((const float4*)dp)[tid];
  float vals[4] = {v4.x, v4.y, v4.z, v4.w};
#pragma unroll
  for (int i = 0; i < 4; ++i) {
    float d = vals[i];
    float fl = floorf(d);
    float t0 = d - fl;
    int k = (int)fl + 60;
    if (t0 >= 2e-5f && t0 <= 1.f - 1.2e-4f) {
      if (k >= 0 && k < 120) atomicAdd(hc + k, 1.0f);
    } else {
      float s0 = 1.f / (1.f + expf(-1e6f * t0));
      float s1 = 1.f / (1.f + expf(1e6f * (1.f - t0)));
      if (k >= 1 && k <= 120) atomicAdd(hc + k - 1, 1.f - s0);
      if (k >= 0 && k < 120)  atomicAdd(hc + k, s0 - s1);
      if (k >= -1 && k < 119) atomicAdd(hc + k + 1, s1);
    }
  }
  __syncthreads();
  for (int f = tid; f < 120; f += 256) {
    float s = 0.f;
#pragma unroll
    for (int l = 0; l < 16; ++l) s += h[l * 121 + f];
    feat[((size_t)b * 120 + f) * 64 + c] = s * (1.f / 1024.f);
  }
}

// ---------------------------------------- weight transpose + BN folding ----
// wt layout: [cg][k30][co][8ci], cg = ci/8, k30 = kh*6+kw (kw==5 zeroed).
template <int CI, int CO>
__global__ __launch_bounds__(256) void wtrans(const float* __restrict__ w,
                                              _Float16* __restrict__ wt) {
  int i = blockIdx.x * 256 + threadIdx.x;
  if (i >= (CI / 8) * 30 * CO * 8) return;
  int c8 = i & 7;
  int t = i >> 3;
  int co = t % CO; t /= CO;
  int k = t % 30;
  int cg = t / 30;
  int ci = cg * 8 + c8;
  int kh = k / 6, kw = k % 6;
  float v = (kw < 5) ? w[((size_t)co * CI + ci) * 25 + kh * 5 + kw] : 0.f;
  wt[i] = (_Float16)v;
}

__global__ __launch_bounds__(256) void bnprep(const float* __restrict__ cb,
                                              const float* __restrict__ s,
                                              const float* __restrict__ b,
                                              const float* __restrict__ m,
                                              const float* __restrict__ v,
                                              float* __restrict__ scale,
                                              float* __restrict__ shift, int n) {
  int i = threadIdx.x;
  if (i < n) {
    float inv = s[i] * rsqrtf(v[i] + 1e-5f);
    scale[i] = inv;
    shift[i] = (cb[i] - m[i]) * inv + b[i];
  }
}

// -------------------------- conv1a: fp32 direct, out grouped-NHWC f16 ------
__global__ __launch_bounds__(256) void conv1a_f16(
    const float* __restrict__ in, const float* __restrict__ wts,
    const float* __restrict__ cb, const float* __restrict__ s_,
    const float* __restrict__ b_, const float* __restrict__ m_,
    const float* __restrict__ v_, _Float16* __restrict__ out) {
  __shared__ __align__(16) float wl[5 * 8 * 20];
  __shared__ __align__(16) float il[12 * 68];
  int tid = threadIdx.x, bid = blockIdx.x;
  int img = bid / 30;
  int r = bid % 30;
  int cob = r / 15;
  int h0 = (r % 15) * 8;
  int cog = tid & 7, wg = (tid >> 3) & 3, hh = tid >> 5;
  float acc[4][16];
#pragma unroll
  for (int i = 0; i < 4; ++i)
#pragma unroll
    for (int j = 0; j < 16; ++j) acc[i][j] = 0.f;
  for (int idx = tid; idx < 32 * 25; idx += 256) {
    int rr = idx % 25, co = idx / 25;
    float v = wts[(cob * 32 + co) * 25 + rr];
    int kh = rr / 5, kw = rr % 5;
    wl[(kh * 8 + (co >> 2)) * 20 + (co & 3) * 5 + kw] = v;
  }
  for (int idx = tid; idx < 12 * 68; idx += 256) {
    int cc = idx % 68, rr = idx / 68;
    int hy = h0 + rr - 2, wx = cc - 2;
    float v = 0.f;
    if (hy >= 0 && hy < 120 && wx >= 0 && wx < 64)
      v = in[(size_t)img * 7680 + hy * 64 + wx];
    il[idx] = v;
  }
  __syncthreads();
#pragma unroll
  for (int kh = 0; kh < 5; ++kh) {
    const float* ir = &il[(hh + kh) * 68 + wg * 16];
    float iv[20];
#pragma unroll
    for (int i = 0; i < 5; ++i) {
      float4 p = *(const float4*)(ir + i * 4);
      iv[i * 4] = p.x; iv[i * 4 + 1] = p.y; iv[i * 4 + 2] = p.z; iv[i * 4 + 3] = p.w;
    }
    const float* wr = &wl[(kh * 8 + cog) * 20];
    float wv[20];
#pragma unroll
    for (int i = 0; i < 5; ++i) {
      float4 p = *(const float4*)(wr + i * 4);
      wv[i * 4] = p.x; wv[i * 4 + 1] = p.y; wv[i * 4 + 2] = p.z; wv[i * 4 + 3] = p.w;
    }
#pragma unroll
    for (int co = 0; co < 4; ++co)
#pragma unroll
      for (int kw = 0; kw < 5; ++kw) {
        float w1 = wv[co * 5 + kw];
#pragma unroll
        for (int w = 0; w < 16; ++w) acc[co][w] += w1 * iv[w + kw];
      }
  }
  int h = h0 + hh;
  int co0 = cob * 32 + cog * 4;
  float inv[4], bia[4];
#pragma unroll
  for (int i = 0; i < 4; ++i) {
    int c = co0 + i;
    inv[i] = s_[c] * rsqrtf(v_[c] + 1e-5f);
    bia[i] = (cb[c] - m_[c]) * inv[i] + b_[c];
  }
  int g = co0 >> 3, off = co0 & 7;
  _Float16* op = out + (((size_t)(img * 8 + g) * 120 + h) * 64) * 8 + off;
#pragma unroll
  for (int w = 0; w < 16; ++w) {
    half4 o;
#pragma unroll
    for (int i = 0; i < 4; ++i)
      o[i] = (_Float16)fmaxf(acc[i][w] * inv[i] + bia[i], 0.f);
    *(half4*)&op[(size_t)(wg * 16 + w) * 8] = o;
  }
}

// ------------------ MFMA implicit-GEMM 5x5 conv + BN + ReLU + maxpool2 -----
// 512 threads / 8 waves. Output is POOLED: grouped [img][CO/8][H/2][W/2][8]
// or (OUT_NCHW) [img][CO][H/2][W/2]. Requires W in {64,32,16}, ROWS even.
template <int CI, int CO, int H, int W, int BLK_M, bool OUT_NCHW>
__global__ __launch_bounds__(512) void conv5_mfma(
    const _Float16* __restrict__ in, const _Float16* __restrict__ wt,
    const float* __restrict__ scale, const float* __restrict__ shift,
    _Float16* __restrict__ out) {
  constexpr int NW_M = BLK_M / 64;
  constexpr int NW_N = 8 / NW_M;
  constexpr int BLK_N = NW_N * 128;
  constexpr int ROWS = BLK_N / W;
  constexpr int TB = (H + ROWS - 1) / ROWS;
  constexpr int NCOB = CO / BLK_M;
  constexpr int HR = ROWS + 4;
  constexpr int HC = W + 4;
  constexpr int CIG = CI / 8;
  constexpr int OH = H / 2, OW = W / 2;
  constexpr int AITER = (HR * HC + 511) / 512;
  constexpr int WBYTES = 30 * BLK_M * 16;
  constexpr int WITER = (WBYTES + 8191) / 8192;
  __shared__ __align__(16) _Float16 Alds[HR * HC * 8 + 8];
  __shared__ __align__(16) _Float16 Wlds[30 * BLK_M * 8];

  int tid = threadIdx.x;
  int bid = blockIdx.x;
  int img = bid / (TB * NCOB);
  int r = bid % (TB * NCOB);
  int tb = r / NCOB;
  int cob = r % NCOB;
  int h0 = tb * ROWS;

  int wid = tid >> 6, l = tid & 63, lo = l & 31, hi = l >> 5;
  int widM = wid / NW_N, widN = wid % NW_N;

  if (tid < 8) Alds[HR * HC * 8 + tid] = (_Float16)0.f;  // zero read-slack

  int wbase[2];
#pragma unroll
  for (int mi = 0; mi < 2; ++mi)
    wbase[mi] = (hi * BLK_M + widM * 64 + mi * 32 + lo) * 8;
  int bbase[4];
#pragma unroll
  for (int j = 0; j < 4; ++j) {
    int pix = widN * 128 + j * 32 + lo;
    bbase[j] = ((pix / W) * HC + (pix % W) + hi) * 8;
  }

  f32x16 acc[2][4];
#pragma unroll
  for (int mi = 0; mi < 2; ++mi)
#pragma unroll
    for (int j = 0; j < 4; ++j) acc[mi][j] = (f32x16){};

#pragma unroll 1
  for (int ci0 = 0; ci0 < CI; ci0 += 8) {
    int cg = ci0 >> 3;
    const _Float16* ing = in + (size_t)(img * CIG + cg) * H * W * 8;
    half8 areg[AITER];
#pragma unroll
    for (int it = 0; it < AITER; ++it) {
      int i = tid + it * 512;
      half8 v = {};
      if (i < HR * HC) {
        int rr = i / HC, cc = i % HC;
        int hy = h0 + rr - 2, wx = cc - 2;
        if (hy >= 0 && hy < H && wx >= 0 && wx < W)
          v = *(const half8*)&ing[(size_t)(hy * W + wx) * 8];
      }
      areg[it] = v;
    }
    const char* wsrc = (const char*)(wt + ((size_t)cg * 30 * CO + cob * BLK_M) * 8);
#pragma unroll
    for (int rr = 0; rr < WITER; ++rr) {
      int f = rr * 8192 + tid * 16;
      if (f < WBYTES) {
        int row = f / (BLK_M * 16);
        int off = f % (BLK_M * 16);
        async_copy16(wsrc + (size_t)row * (CO * 16) + off,
                     (char*)Wlds + (rr * 8192 + wid * 1024));
      }
    }
#pragma unroll
    for (int it = 0; it < AITER; ++it) {
      int i = tid + it * 512;
      if (i < HR * HC) *(half8*)&Alds[i * 8] = areg[it];
    }
    __syncthreads();
#pragma unroll
    for (int kh = 0; kh < 5; ++kh) {
#pragma unroll
      for (int kwb = 0; kwb < 3; ++kwb) {
        half8 af[2], bf[4];
#pragma unroll
        for (int mi = 0; mi < 2; ++mi)
          af[mi] = *(const half8*)&Wlds[wbase[mi] + (kh * 6 + 2 * kwb) * BLK_M * 8];
#pragma unroll
        for (int j = 0; j < 4; ++j)
          bf[j] = *(const half8*)&Alds[bbase[j] + (kh * HC + 2 * kwb) * 8];
#pragma unroll
        for (int mi = 0; mi < 2; ++mi)
#pragma unroll
          for (int j = 0; j < 4; ++j)
            acc[mi][j] = __builtin_amdgcn_mfma_f32_32x32x16_f16(
                af[mi], bf[j], acc[mi][j], 0, 0, 0);
      }
    }
    __syncthreads();
  }

  // ---- fused BN + ReLU + 2x2 maxpool epilogue ----
  if (!OUT_NCHW) {
    // W==64: rows widN*2+{0,1} = j pairs (0,2),(1,3); cols p*32+lo.
    // W==32: rows widN*4+j   = j pairs (0,1),(2,3); cols lo.
    constexpr int CGO = CO / 8;
    int gbase = (cob * BLK_M + widM * 64) >> 3;
    bool lane_ok = ((lo & 1) == 0);
#pragma unroll
    for (int mi = 0; mi < 2; ++mi) {
#pragma unroll
      for (int r4 = 0; r4 < 4; ++r4) {
        int g = gbase + mi * 4 + r4;
        int co0 = g * 8 + hi * 4;
        float4 sv = *(const float4*)&scale[co0];
        float4 tv = *(const float4*)&shift[co0];
        float sa[4] = {sv.x, sv.y, sv.z, sv.w};
        float ta[4] = {tv.x, tv.y, tv.z, tv.w};
#pragma unroll
        for (int p = 0; p < 2; ++p) {
          int ja = (W == 64) ? p : 2 * p;
          int jb = (W == 64) ? p + 2 : 2 * p + 1;
          int orow = (W == 64) ? (h0 >> 1) + widN : (h0 >> 1) + widN * 2 + p;
          int ocol = (W == 64) ? p * 16 + (lo >> 1) : (lo >> 1);
          half4 o;
#pragma unroll
          for (int c = 0; c < 4; ++c) {
            int reg = r4 * 4 + c;
            float v0 = fmaxf(acc[mi][ja][reg] * sa[c] + ta[c], 0.f);
            float v1 = fmaxf(acc[mi][jb][reg] * sa[c] + ta[c], 0.f);
            float m = fmaxf(v0, v1);
            m = fmaxf(m, __shfl_xor(m, 1, 64));
            o[c] = (_Float16)m;
          }
          if (lane_ok && orow < OH)
            *(half4*)&out[(((size_t)(img * CGO + g) * OH + orow) * OW + ocol) * 8 +
                          hi * 4] = o;
        }
      }
    }
  } else {
    // W==16: rows widN*8 + 2j + (lo>>4); row pair = lane^16, col pair = lane^1.
    bool lane_ok = ((lo & 1) == 0) && (lo < 16);
#pragma unroll
    for (int mi = 0; mi < 2; ++mi) {
#pragma unroll
      for (int reg = 0; reg < 16; ++reg) {
        int co = cob * BLK_M + widM * 64 + mi * 32 + (reg & 3) + 8 * (reg >> 2) + 4 * hi;
        float s = scale[co], t = shift[co];
#pragma unroll
        for (int j = 0; j < 4; ++j) {
          float v = fmaxf(acc[mi][j][reg] * s + t, 0.f);
          float m = fmaxf(v, __shfl_xor(v, 16, 64));
          m = fmaxf(m, __shfl_xor(m, 1, 64));
          int orow = (h0 >> 1) + widN * 4 + j;
          if (lane_ok && orow < OH)
            out[((size_t)(img * CO + co) * OH + orow) * OW + ((lo & 15) >> 1)] =
                (_Float16)m;
        }
      }
    }
  }
}

// --------------------------------------------------- fc1: f16 MFMA split-K -
// 240 K-splits x 2 N-tiles = 480 blocks. part[ks][n512][img128].
__global__ __launch_bounds__(256, 2) void fc1_mfma(const float* __restrict__ qv,
                                                   const _Float16* __restrict__ p3,
                                                   const float* __restrict__ w,
                                                   float* __restrict__ part) {
  __shared__ __align__(16) _Float16 Wl[8 * 256 * 8];  // [k8][n_loc][8]
  __shared__ __align__(16) _Float16 Bl[8 * 128 * 8];  // [k8][img][8]
  int tid = threadIdx.x;
  int ks = blockIdx.x >> 1, mt = blockIdx.x & 1;
  int wid = tid >> 6, l = tid & 63, lo = l & 31, hi = l >> 5;
  f32x16 acc[2][4];
#pragma unroll
  for (int mi = 0; mi < 2; ++mi)
#pragma unroll
    for (int j = 0; j < 4; ++j) acc[mi][j] = (f32x16){};

#pragma unroll 1
  for (int i3 = 0; i3 < 3; ++i3) {
    int c = ks + 240 * i3;
    if (c > 480) break;
    for (int idx = tid; idx < 2048; idx += 256) {
      int n_loc = idx >> 3, k8 = idx & 7;
      int n = mt * 256 + n_loc;
      half8 v = {};
      if (n < 500) {
        const float* src = w + (size_t)n * 30784 + c * 64 + k8 * 8;
        float4 f0 = *(const float4*)src;
        float4 f1 = *(const float4*)(src + 4);
        v[0] = (_Float16)f0.x; v[1] = (_Float16)f0.y;
        v[2] = (_Float16)f0.z; v[3] = (_Float16)f0.w;
        v[4] = (_Float16)f1.x; v[5] = (_Float16)f1.y;
        v[6] = (_Float16)f1.z; v[7] = (_Float16)f1.w;
      }
      *(half8*)&Wl[(size_t)(k8 * 256 + n_loc) * 8] = v;
    }
    for (int idx = tid; idx < 1024; idx += 256) {
      int img = idx >> 3, k8 = idx & 7;
      half8 v;
      if (c == 0) {
        const float* src = qv + img * 64 + k8 * 8;
        float4 f0 = *(const float4*)src;
        float4 f1 = *(const float4*)(src + 4);
        v[0] = (_Float16)f0.x; v[1] = (_Float16)f0.y;
        v[2] = (_Float16)f0.z; v[3] = (_Float16)f0.w;
        v[4] = (_Float16)f1.x; v[5] = (_Float16)f1.y;
        v[6] = (_Float16)f1.z; v[7] = (_Float16)f1.w;
      } else {
        v = *(const half8*)&p3[(size_t)img * 30720 + (c * 64 - 64) + k8 * 8];
      }
      *(half8*)&Bl[(size_t)(k8 * 128 + img) * 8] = v;
    }
    __syncthreads();
#pragma unroll
    for (int ks16 = 0; ks16 < 4; ++ks16) {
      half8 af[2], bf[4];
#pragma unroll
      for (int mi = 0; mi < 2; ++mi)
        af[mi] = *(const half8*)&Wl[(size_t)((ks16 * 2 + hi) * 256 + wid * 64 +
                                             mi * 32 + lo) * 8];
#pragma unroll
      for (int j = 0; j < 4; ++j)
        bf[j] = *(const half8*)&Bl[(size_t)((ks16 * 2 + hi) * 128 + j * 32 + lo) * 8];
#pragma unroll
      for (int mi = 0; mi < 2; ++mi)
#pragma unroll
        for (int j = 0; j < 4; ++j)
          acc[mi][j] = __builtin_amdgcn_mfma_f32_32x32x16_f16(
              af[mi], bf[j], acc[mi][j], 0, 0, 0);
    }
    __syncthreads();
  }
#pragma unroll
  for (int mi = 0; mi < 2; ++mi)
#pragma unroll
    for (int reg = 0; reg < 16; ++reg) {
      int n = mt * 256 + wid * 64 + mi * 32 + (reg & 3) + 8 * (reg >> 2) + 4 * hi;
#pragma unroll
      for (int j = 0; j < 4; ++j)
        part[((size_t)ks * 512 + n) * 128 + j * 32 + lo] = acc[mi][j][reg];
    }
}

__global__ __launch_bounds__(256) void fc1_reduce(const float* __restrict__ part,
                                                  const float* __restrict__ bias,
                                                  float* __restrict__ out) {
  int idx = blockIdx.x * 256 + threadIdx.x;  // 65536 = 512 n x 128 img
  int img = idx & 127, n = idx >> 7;
  float s = 0.f;
#pragma unroll 8
  for (int ks = 0; ks < 240; ++ks) s += part[((size_t)ks * 512 + n) * 128 + img];
  out[n * 128 + img] = (n < 500) ? fmaxf(s + bias[n], 0.f) : 0.f;
}

// -------------------------------------------------------- fc2 / fc3 --------
__global__ __launch_bounds__(256) void fc2_kernel(const float* __restrict__ qv,
                                                  const float* __restrict__ fc1o,
                                                  const float* __restrict__ w,
                                                  const float* __restrict__ bias,
                                                  float* __restrict__ out) {
  int idx = blockIdx.x * 256 + threadIdx.x;
  if (idx >= 128 * 500) return;
  int m = idx & 127, n = idx >> 7;
  const float* wr = w + (size_t)n * 564;
  float acc = 0.f;
#pragma unroll 8
  for (int k = 0; k < 64; ++k) acc += qv[m * 64 + k] * wr[k];
#pragma unroll 4
  for (int k = 0; k < 500; ++k) acc += fc1o[k * 128 + m] * wr[64 + k];
  out[n * 128 + m] = fmaxf(acc + bias[n], 0.f);
}

__global__ __launch_bounds__(256) void fc3_kernel(const float* __restrict__ qv,
                                                  const float* __restrict__ fc2o,
                                                  const float* __restrict__ w,
                                                  const float* __restrict__ bias,
                                                  float* __restrict__ out) {
  int tid = threadIdx.x;
  int m = tid >> 1, n = tid & 1;
  const float* wr = w + (size_t)n * 564;
  float acc = 0.f;
#pragma unroll 8
  for (int k = 0; k < 64; ++k) acc += qv[m * 64 + k] * wr[k];
#pragma unroll 4
  for (int k = 0; k < 500; ++k) acc += fc2o[k * 128 + m] * wr[64 + k];
  out[m * 2 + n] = acc + bias[n];
}

// ----------------------------------------------------------- launcher ------
extern "C" void kernel_launch(void* const* d_in, const int* in_sizes, int n_in,
                              void* d_out, int out_size, void* d_ws, size_t ws_size,
                              hipStream_t stream) {
  (void)in_sizes; (void)n_in; (void)out_size; (void)ws_size;
  const float* x      = (const float*)d_in[0];
  const float* qv     = (const float*)d_in[1];
  const float* basis  = (const float*)d_in[2];
  const float* c1aw   = (const float*)d_in[3];
  const float* c1ab   = (const float*)d_in[4];
  const float* c1bw   = (const float*)d_in[5];
  const float* c1bb   = (const float*)d_in[6];
  const float* c2aw   = (const float*)d_in[7];
  const float* c2ab   = (const float*)d_in[8];
  const float* c3aw   = (const float*)d_in[9];
  const float* c3ab   = (const float*)d_in[10];
  const float* bn1a_s = (const float*)d_in[11];
  const float* bn1a_b = (const float*)d_in[12];
  const float* bn1a_m = (const float*)d_in[13];
  const float* bn1a_v = (const float*)d_in[14];
  const float* bn1b_s = (const float*)d_in[15];
  const float* bn1b_b = (const float*)d_in[16];
  const float* bn1b_m = (const float*)d_in[17];
  const float* bn1b_v = (const float*)d_in[18];
  const float* bn2a_s = (const float*)d_in[19];
  const float* bn2a_b = (const float*)d_in[20];
  const float* bn2a_m = (const float*)d_in[21];
  const float* bn2a_v = (const float*)d_in[22];
  const float* bn3a_s = (const float*)d_in[23];
  const float* bn3a_b = (const float*)d_in[24];
  const float* bn3a_m = (const float*)d_in[25];
  const float* bn3a_v = (const float*)d_in[26];
  const float* fc1w   = (const float*)d_in[27];
  const float* fc1b   = (const float*)d_in[28];
  const float* fc2w   = (const float*)d_in[29];
  const float* fc2b   = (const float*)d_in[30];
  const float* fc3w   = (const float*)d_in[31];
  const float* fc3b   = (const float*)d_in[32];

  // ---- workspace (fl units), peak ~29.6M fl = 118 MB ----
  float* ws = (float*)d_ws;
  float* feat = ws;                                   //   983,040
  _Float16* wt1b = (_Float16*)(ws + 1000000);         //   122,880 h
  _Float16* wt2a = (_Float16*)(ws + 1070000);         //   245,760 h
  _Float16* wt3a = (_Float16*)(ws + 1200000);         //   983,040 h
  float* sc1b = ws + 1700000; float* sh1b = ws + 1700100;
  float* sc2a = ws + 1700200; float* sh2a = ws + 1700400;
  float* sc3a = ws + 1700600; float* sh3a = ws + 1701000;
  _Float16* p1 = (_Float16*)(ws + 1710000);           // 15,728,640 h (full)
  float* S = ws + 9600000;
  float* dct     = S;                                 //  8,388,608 (dead early)
  _Float16* a1c  = (_Float16*)S;                      // 31,457,280 h (64-img chunk)
  _Float16* p2   = (_Float16*)(ws + 25400000);        //  7,864,320 h (full)
  _Float16* p3   = (_Float16*)(ws + 1710000);         //  3,932,160 h (p1 slot)
  float* f1p  = S;                                    // 15,728,640 fl (a1c dead)
  float* f1o  = ws + 29400000;                        //     65,536
  float* f2o  = ws + 29500000;                        //     65,536

  wtrans<64, 64><<<480, 256, 0, stream>>>(c1bw, wt1b);
  wtrans<64, 128><<<960, 256, 0, stream>>>(c2aw, wt2a);
  wtrans<128, 256><<<3840, 256, 0, stream>>>(c3aw, wt3a);
  bnprep<<<1, 256, 0, stream>>>(c1bb, bn1b_s, bn1b_b, bn1b_m, bn1b_v, sc1b, sh1b, 64);
  bnprep<<<1, 256, 0, stream>>>(c2ab, bn2a_s, bn2a_b, bn2a_m, bn2a_v, sc2a, sh2a, 128);
  bnprep<<<1, 256, 0, stream>>>(c3ab, bn3a_s, bn3a_b, bn3a_m, bn3a_v, sc3a, sh3a, 256);

  dct_kernel<<<512, 256, 0, stream>>>(x, basis, dct);
  hist_kernel<<<128 * 64, 256, 0, stream>>>(dct, feat);

  // ---- conv1a + conv1b(MFMA, pooled out) : 2 chunks of 64 images ----
  for (int c = 0; c < 2; ++c) {
    const float* fin = feat + (size_t)c * 64 * 120 * 64;
    _Float16* pout = p1 + (size_t)c * 64 * 8 * 60 * 32 * 8;
    conv1a_f16<<<64 * 30, 256, 0, stream>>>(fin, c1aw, c1ab, bn1a_s, bn1a_b,
                                            bn1a_m, bn1a_v, a1c);
    conv5_mfma<64, 64, 120, 64, 64, false><<<64 * 8, 512, 0, stream>>>(
        a1c, wt1b, sc1b, sh1b, pout);
  }

  // ---- conv2a (full batch, pooled out) ----
  conv5_mfma<64, 128, 60, 32, 128, false><<<128 * 4, 512, 0, stream>>>(
      p1, wt2a, sc2a, sh2a, p2);

  // ---- conv3a (full batch, pooled NCHW out) ----
  conv5_mfma<128, 256, 30, 16, 128, true><<<128 * 2, 512, 0, stream>>>(
      p2, wt3a, sc3a, sh3a, p3);

  // ---- FC stack ----
  fc1_mfma<<<480, 256, 0, stream>>>(qv, p3, fc1w, f1p);
  fc1_reduce<<<256, 256, 0, stream>>>(f1p, fc1b, f1o);
  fc2_kernel<<<250, 256, 0, stream>>>(qv, f1o, fc2w, fc2b, f2o);
  fc3_kernel<<<1, 256, 0, stream>>>(qv, f2o, fc3w, fc3b, (float*)d_out);
}